// Round 2
// 521.943 us; speedup vs baseline: 1.0417x; 1.0417x over previous
//
#include <hip/hip_runtime.h>
#include <cmath>

namespace {

constexpr int CH    = 512;
constexpr int NPIX  = 4096;   // 64*64

typedef _Float16 half8 __attribute__((ext_vector_type(8)));
typedef _Float16 half4 __attribute__((ext_vector_type(4)));
typedef float    f32x4 __attribute__((ext_vector_type(4)));

__device__ __forceinline__ float sigmoidf_(float v) { return 1.0f / (1.0f + expf(-v)); }

// ======================= K0: fp32 -> (hi, lo*1024) f16 split ==============
__global__ __launch_bounds__(256) void k_split(
    const float4* __restrict__ in, half4* __restrict__ hi,
    half4* __restrict__ lo, int n4)
{
    int i = blockIdx.x * 256 + threadIdx.x;
    if (i >= n4) return;
    float4 v = in[i];
    half4 h, l;
    h[0] = (_Float16)v.x; l[0] = (_Float16)((v.x - (float)h[0]) * 1024.0f);
    h[1] = (_Float16)v.y; l[1] = (_Float16)((v.y - (float)h[1]) * 1024.0f);
    h[2] = (_Float16)v.z; l[2] = (_Float16)((v.z - (float)h[2]) * 1024.0f);
    h[3] = (_Float16)v.w; l[3] = (_Float16)((v.w - (float)h[3]) * 1024.0f);
    hi[i] = h; lo[i] = l;
}

// ======================= K1: qk = x @ qk_w^T + qk_b (split-f16 MFMA) ======
__global__ __launch_bounds__(256, 2) void k_gemm_mfma(
    const _Float16* __restrict__ Ahi, const _Float16* __restrict__ Alo,
    const _Float16* __restrict__ Bhi, const _Float16* __restrict__ Blo,
    const float* __restrict__ bias, float* __restrict__ out)
{
    __shared__ _Float16 lds[4 * 128 * 32];   // Ahi | Alo | Bhi | Blo tiles
    const int t    = threadIdx.x;
    const int wave = t >> 6;
    const int lane = t & 63;
    const int bm   = blockIdx.x;             // 0..255
    const int bn   = blockIdx.y;             // 0..7

    const _Float16* src;
    switch (wave) {
        case 0: src = Ahi + (size_t)bm * 128 * 512; break;
        case 1: src = Alo + (size_t)bm * 128 * 512; break;
        case 2: src = Bhi + (size_t)bn * 128 * 512; break;
        default: src = Blo + (size_t)bn * 128 * 512; break;
    }
    const _Float16* srcLane = src + (size_t)(lane >> 2) * 512 + (lane & 3) * 8;
    _Float16* ldsW = lds + wave * 4096;

    const int wm = wave >> 1, wn = wave & 1;
    const int mrow = lane & 15;
    const int kq   = (lane >> 4) * 8;
    const _Float16* aH = lds         + (wm * 64 + mrow) * 32 + kq;
    const _Float16* aL = lds + 4096  + (wm * 64 + mrow) * 32 + kq;
    const _Float16* bH = lds + 8192  + (wn * 64 + mrow) * 32 + kq;
    const _Float16* bL = lds + 12288 + (wn * 64 + mrow) * 32 + kq;

    f32x4 acc0[4][4], acc1[4][4];
    #pragma unroll
    for (int i = 0; i < 4; i++)
        #pragma unroll
        for (int j = 0; j < 4; j++) { acc0[i][j] = (f32x4)0.0f; acc1[i][j] = (f32x4)0.0f; }

    for (int k0 = 0; k0 < 16; k0++) {
        const _Float16* g = srcLane + k0 * 32;
        #pragma unroll
        for (int r = 0; r < 8; r++) {
            __builtin_amdgcn_global_load_lds(
                (const __attribute__((address_space(1))) void*)(g + (size_t)r * 16 * 512),
                (__attribute__((address_space(3))) void*)(ldsW + r * 512),
                16, 0, 0);
        }
        __syncthreads();

        half8 ah[4], al[4], bh[4], bl[4];
        #pragma unroll
        for (int i = 0; i < 4; i++) {
            ah[i] = *(const half8*)(aH + i * 16 * 32);
            al[i] = *(const half8*)(aL + i * 16 * 32);
            bh[i] = *(const half8*)(bH + i * 16 * 32);
            bl[i] = *(const half8*)(bL + i * 16 * 32);
        }
        #pragma unroll
        for (int i = 0; i < 4; i++)
            #pragma unroll
            for (int j = 0; j < 4; j++) {
                acc0[i][j] = __builtin_amdgcn_mfma_f32_16x16x32_f16(ah[i], bh[j], acc0[i][j], 0, 0, 0);
                acc1[i][j] = __builtin_amdgcn_mfma_f32_16x16x32_f16(ah[i], bl[j], acc1[i][j], 0, 0, 0);
                acc1[i][j] = __builtin_amdgcn_mfma_f32_16x16x32_f16(al[i], bh[j], acc1[i][j], 0, 0, 0);
            }
        __syncthreads();
    }

    const int ccol = lane & 15;
    const int crow = (lane >> 4) * 4;
    #pragma unroll
    for (int j = 0; j < 4; j++) {
        int col = bn * 128 + wn * 64 + j * 16 + ccol;
        float bv = bias[col];
        #pragma unroll
        for (int i = 0; i < 4; i++) {
            size_t row0 = (size_t)bm * 128 + wm * 64 + i * 16 + crow;
            #pragma unroll
            for (int r = 0; r < 4; r++) {
                float v = acc0[i][j][r] + acc1[i][j][r] * (1.0f / 1024.0f) + bv;
                out[(row0 + r) * 1024 + col] = v;
            }
        }
    }
}

// ======================= K2: spatial gate — sliding window, w-quartered ====
__global__ __launch_bounds__(512) void k_spatial(
    const float* __restrict__ qk,
    const float* __restrict__ dw_w_q, const float* __restrict__ dw_b_q,
    const float* __restrict__ bn_g_q, const float* __restrict__ bn_b_q,
    const float* __restrict__ pw_q,
    const float* __restrict__ dw_w_k, const float* __restrict__ dw_b_k,
    const float* __restrict__ bn_g_k, const float* __restrict__ bn_b_k,
    const float* __restrict__ pw_k,
    float* __restrict__ s_sp_q, float* __restrict__ s_sp_k,
    float* __restrict__ pool_q, float* __restrict__ pool_k)
{
    const int which = blockIdx.y;
    const int bx = blockIdx.x;            // 0..2047
    const int b  = bx >> 8;
    const int h  = (bx >> 2) & 63;
    const int w0 = (bx & 3) * 16;
    const int c  = threadIdx.x;
    const float* dw_w = which ? dw_w_k : dw_w_q;
    const float* dw_b = which ? dw_b_k : dw_b_q;
    const float* bn_g = which ? bn_g_k : bn_g_q;
    const float* bn_b = which ? bn_b_k : bn_b_q;
    const float* pw   = which ? pw_k   : pw_q;
    float*       s_sp = which ? s_sp_k : s_sp_q;
    float*       pool = which ? pool_k : pool_q;

    float w9[9];
    #pragma unroll
    for (int j = 0; j < 9; j++) w9[j] = dw_w[c * 9 + j];
    const float bconv = dw_b[c];
    const float bns   = bn_g[c] * (1.0f / sqrtf(1.00001f));
    const float bnb   = bn_b[c];
    const float pwc   = pw[c];

    __shared__ float wavepart[16][8];
    __shared__ float s_row[16];
    const int lane = c & 63, wid = c >> 6;
    const float* inb  = qk + (size_t)b * NPIX * 1024 + (which ? 512 : 0);
    const float* row0 = inb + (size_t)(h * 64) * 1024 + c;
    const float* rowm = row0 - (ptrdiff_t)64 * 1024;   // h-1 (deref-guarded)
    const float* rowp = row0 + (ptrdiff_t)64 * 1024;   // h+1
    const bool hm_ok = (h > 0), hp_ok = (h < 63);

    float x0m, x00, x0p, x1m, x10, x1p, x2m, x20, x2p;
    float cent[16];

    auto LD3 = [&](int wg, float& vm, float& v0, float& vp) {
        bool wok = (wg >= 0) && (wg < 64);
        ptrdiff_t o = (ptrdiff_t)wg * 1024;
        vm = (wok && hm_ok) ? rowm[o] : 0.0f;
        v0 =  wok           ? row0[o] : 0.0f;
        vp = (wok && hp_ok) ? rowp[o] : 0.0f;
    };

    LD3(w0 - 1, x0m, x1m, x2m);
    LD3(w0,     x00, x10, x20);

    #pragma unroll
    for (int i = 0; i < 16; i++) {
        LD3(w0 + i + 1, x0p, x1p, x2p);
        float y = bconv;
        y = fmaf(x0m, w9[0], y); y = fmaf(x00, w9[1], y); y = fmaf(x0p, w9[2], y);
        y = fmaf(x1m, w9[3], y); y = fmaf(x10, w9[4], y); y = fmaf(x1p, w9[5], y);
        y = fmaf(x2m, w9[6], y); y = fmaf(x20, w9[7], y); y = fmaf(x2p, w9[8], y);
        y = fmaxf(fmaf(y, bns, bnb), 0.0f);
        cent[i] = x10;
        float contrib = y * pwc;
        #pragma unroll
        for (int o = 32; o > 0; o >>= 1) contrib += __shfl_down(contrib, o, 64);
        if (lane == 0) wavepart[i][wid] = contrib;
        x0m = x00; x00 = x0p;
        x1m = x10; x10 = x1p;
        x2m = x20; x20 = x2p;
    }
    __syncthreads();
    if (c < 16) {
        float s = 0.0f;
        #pragma unroll
        for (int j = 0; j < 8; j++) s += wavepart[c][j];
        s = sigmoidf_(s);
        s_row[c] = s;
        s_sp[(size_t)b * NPIX + h * 64 + w0 + c] = s;
    }
    __syncthreads();
    float pacc = 0.0f;
    #pragma unroll
    for (int i = 0; i < 16; i++) pacc = fmaf(cent[i], s_row[i], pacc);
    atomicAdd(&pool[(size_t)b * CH + c], pacc);
}

// ======================= K3: channel sigmoid ===============================
__global__ __launch_bounds__(256) void k_chsig(
    const float* __restrict__ pool_q, const float* __restrict__ pool_k,
    const float* __restrict__ qch_w,  const float* __restrict__ kch_w,
    float* __restrict__ sch_q, float* __restrict__ sch_k)
{
    int id    = blockIdx.x;           // 0..2047
    int which = id >> 10;
    int rem   = id & 1023;
    int b     = rem >> 7;             // 0..7
    int og    = rem & 127;            // 0..127
    int wid   = threadIdx.x >> 6, lane = threadIdx.x & 63;
    int o     = og * 4 + wid;
    const float* pool = which ? pool_k : pool_q;
    const float* Wt   = which ? kch_w  : qch_w;
    float s = 0.0f;
    for (int cc = lane; cc < CH; cc += 64) s = fmaf(pool[b * CH + cc], Wt[o * CH + cc], s);
    #pragma unroll
    for (int off = 32; off > 0; off >>= 1) s += __shfl_down(s, off, 64);
    if (lane == 0)
        (which ? sch_k : sch_q)[b * CH + o] = sigmoidf_(s * (1.0f / 4096.0f));
}

// ======================= K4: kv accumulate, rope(k) fused in-register ======
// Block = (b*16+head, n-tile). Each thread stages a float4 of 4 consecutive
// channels = 2 rope pairs -> gate/elu/rope computed fully in-register before
// the LDS store. kmean accumulated here (channel fixed per thread).
__global__ __launch_bounds__(256) void k_kv(
    const float* __restrict__ qk, const float* __restrict__ x,
    const float* __restrict__ s_sp_k, const float* __restrict__ sch_k,
    const float* __restrict__ cosT,   const float* __restrict__ sinT,
    float* __restrict__ kv, float* __restrict__ kmean)
{
    const int bh = blockIdx.x;      // 0..127
    const int b  = bh >> 4, hh = bh & 15;
    const int n0 = blockIdx.y * 512;
    __shared__ float kt[32][33];
    __shared__ float vt[32][33];
    const int t  = threadIdx.x;
    const int e  = t & 31, d0 = (t >> 5) * 4;
    const int nn  = t >> 3;
    const int cc4 = (t & 7) * 4;
    const int cg  = hh * 32 + cc4;          // global channel of lane's quad
    const int kidx = cg >> 1;               // rope pair index (even)

    const float sch0 = sch_k[b * CH + cg + 0];
    const float sch1 = sch_k[b * CH + cg + 1];
    const float sch2 = sch_k[b * CH + cg + 2];
    const float sch3 = sch_k[b * CH + cg + 3];

    float km0 = 0.f, km1 = 0.f, km2 = 0.f, km3 = 0.f;
    float acc[4] = {0.f, 0.f, 0.f, 0.f};
    for (int s = 0; s < 512; s += 32) {
        const int n = n0 + s + nn;
        size_t rowbase = (size_t)(b * NPIX + n);
        float4 kvv = *(const float4*)(qk + rowbase * 1024 + 512 + cg);
        const float ssp = s_sp_k[(size_t)b * NPIX + n];
        float g0 = kvv.x * ssp * sch0;
        float g1 = kvv.y * ssp * sch1;
        float g2 = kvv.z * ssp * sch2;
        float g3 = kvv.w * ssp * sch3;
        float e0 = g0 > 0.0f ? g0 + 1.0f : expf(g0);
        float e1 = g1 > 0.0f ? g1 + 1.0f : expf(g1);
        float e2 = g2 > 0.0f ? g2 + 1.0f : expf(g2);
        float e3 = g3 > 0.0f ? g3 + 1.0f : expf(g3);
        const float cs0 = cosT[(size_t)n * 256 + kidx];
        const float sn0 = sinT[(size_t)n * 256 + kidx];
        const float cs1 = cosT[(size_t)n * 256 + kidx + 1];
        const float sn1 = sinT[(size_t)n * 256 + kidx + 1];
        float r0 = fmaf(cs0, e0, -(sn0 * e1));
        float r1 = fmaf(sn0, e0,   cs0 * e1);
        float r2 = fmaf(cs1, e2, -(sn1 * e3));
        float r3 = fmaf(sn1, e2,   cs1 * e3);
        kt[nn][cc4] = r0; kt[nn][cc4+1] = r1; kt[nn][cc4+2] = r2; kt[nn][cc4+3] = r3;
        km0 += r0; km1 += r1; km2 += r2; km3 += r3;
        float4 vv  = *(const float4*)(x + rowbase * 512 + cg);
        vt[nn][cc4] = vv.x; vt[nn][cc4+1] = vv.y; vt[nn][cc4+2] = vv.z; vt[nn][cc4+3] = vv.w;
        __syncthreads();
        #pragma unroll
        for (int q = 0; q < 32; q++) {
            float vq = vt[q][e];
            acc[0] = fmaf(kt[q][d0    ], vq, acc[0]);
            acc[1] = fmaf(kt[q][d0 + 1], vq, acc[1]);
            acc[2] = fmaf(kt[q][d0 + 2], vq, acc[2]);
            acc[3] = fmaf(kt[q][d0 + 3], vq, acc[3]);
        }
        __syncthreads();
    }
    #pragma unroll
    for (int i = 0; i < 4; i++)
        atomicAdd(&kv[((size_t)bh * 32 + d0 + i) * 32 + e], acc[i]);
    atomicAdd(&kmean[(size_t)b * CH + cg + 0], km0);
    atomicAdd(&kmean[(size_t)b * CH + cg + 1], km1);
    atomicAdd(&kmean[(size_t)b * CH + cg + 2], km2);
    atomicAdd(&kmean[(size_t)b * CH + cg + 3], km3);
}

// ======================= K5: out = (q_r @ kv)*z + lepe — rope(q) fused =====
// Reads RAW qk q-half; gate/elu/rope applied per pixel (partner channel via
// one shfl_xor). kv column in registers, q broadcast via width-32 shfl,
// sliding-window lepe conv. Zero __syncthreads.
__global__ __launch_bounds__(512) void k_final(
    const float* __restrict__ qk, const float* __restrict__ x,
    const float* __restrict__ kvbuf, const float* __restrict__ kmean,
    const float* __restrict__ s_sp_q, const float* __restrict__ sch_q,
    const float* __restrict__ cosT,   const float* __restrict__ sinT,
    const float* __restrict__ lepe_w, const float* __restrict__ lepe_b,
    float* __restrict__ out)
{
    const int bx = blockIdx.x;            // 0..1023
    const int b  = bx >> 7;
    const int h  = (bx >> 1) & 63;
    const int w0 = (bx & 1) * 32;
    const int c  = threadIdx.x;
    const int e  = c & 31;
    const int head = c >> 5;
    const int kidx = c >> 1;
    const int odd  = c & 1;

    float kvreg[32];
    #pragma unroll
    for (int d = 0; d < 32; d++)
        kvreg[d] = kvbuf[((size_t)b * 16 + head) * 1024 + d * 32 + e] * (1.0f / 4096.0f);
    const float km = kmean[(size_t)b * CH + c] * (1.0f / 4096.0f);
    const float schc = sch_q[(size_t)b * CH + c];
    float w9[9];
    #pragma unroll
    for (int j = 0; j < 9; j++) w9[j] = lepe_w[c * 9 + j];
    const float lb = lepe_b[c];

    const float* xr0 = x + ((size_t)b * NPIX + h * 64) * 512 + c;
    const float* xrm = xr0 - (ptrdiff_t)64 * 512;
    const float* xrp = xr0 + (ptrdiff_t)64 * 512;
    const bool hm_ok = (h > 0), hp_ok = (h < 63);
    const float* qkb = qk + ((size_t)b * NPIX + h * 64) * 1024 + c;
    const float* ssb = s_sp_q + (size_t)b * NPIX + h * 64;
    const float* csb = cosT + (size_t)(h * 64) * 256 + kidx;
    const float* snb = sinT + (size_t)(h * 64) * 256 + kidx;
    float* outb = out + ((size_t)b * NPIX + h * 64) * 512 + c;

    float x0m, x00, x0p, x1m, x10, x1p, x2m, x20, x2p;
    auto LD3 = [&](int wg, float& vm, float& v0, float& vp) {
        bool wok = (wg >= 0) && (wg < 64);
        ptrdiff_t o = (ptrdiff_t)wg * 512;
        vm = (wok && hm_ok) ? xrm[o] : 0.0f;
        v0 =  wok           ? xr0[o] : 0.0f;
        vp = (wok && hp_ok) ? xrp[o] : 0.0f;
    };
    LD3(w0 - 1, x0m, x1m, x2m);
    LD3(w0,     x00, x10, x20);

    for (int i = 0; i < 32; i++) {
        const int wg = w0 + i;
        float x0p_, x1p_, x2p_;
        LD3(wg + 1, x0p_, x1p_, x2p_);
        x0p = x0p_; x1p = x1p_; x2p = x2p_;

        // --- fused gate + elu + rope for q ---
        float qraw = qkb[(size_t)wg * 1024];
        float ssp  = ssb[wg];
        float g    = qraw * ssp * schc;
        float eV   = g > 0.0f ? g + 1.0f : expf(g);
        float part = __shfl_xor(eV, 1, 64);
        float cs   = csb[(size_t)wg * 256];
        float sn   = snb[(size_t)wg * 256];
        float qv   = odd ? fmaf(sn, part, cs * eV) : fmaf(cs, eV, -(sn * part));

        float den = qv * km;
        #pragma unroll
        for (int off = 16; off > 0; off >>= 1) den += __shfl_xor(den, off, 32);
        float z = 1.0f / (den + 1e-6f);
        float num = 0.0f;
        #pragma unroll
        for (int d = 0; d < 32; d++) num = fmaf(__shfl(qv, d, 32), kvreg[d], num);

        float lp = lb;
        lp = fmaf(x0m, w9[0], lp); lp = fmaf(x00, w9[1], lp); lp = fmaf(x0p, w9[2], lp);
        lp = fmaf(x1m, w9[3], lp); lp = fmaf(x10, w9[4], lp); lp = fmaf(x1p, w9[5], lp);
        lp = fmaf(x2m, w9[6], lp); lp = fmaf(x20, w9[7], lp);

        outb[(size_t)wg * 512] = fmaf(num, z, fmaf(x2p, w9[8], lp));

        x0m = x00; x00 = x0p;
        x1m = x10; x10 = x1p;
        x2m = x20; x20 = x2p;
    }
}

} // namespace

extern "C" void kernel_launch(void* const* d_in, const int* in_sizes, int n_in,
                              void* d_out, int out_size, void* d_ws, size_t ws_size,
                              hipStream_t stream)
{
    (void)in_sizes; (void)n_in; (void)out_size; (void)ws_size;
    const float* x        = (const float*)d_in[0];
    const float* qk_w     = (const float*)d_in[1];
    const float* qk_b     = (const float*)d_in[2];
    const float* qsp_dw_w = (const float*)d_in[3];
    const float* qsp_dw_b = (const float*)d_in[4];
    const float* qsp_bn_g = (const float*)d_in[5];
    const float* qsp_bn_b = (const float*)d_in[6];
    const float* qsp_pw_w = (const float*)d_in[7];
    const float* qch_w    = (const float*)d_in[8];
    const float* ksp_dw_w = (const float*)d_in[9];
    const float* ksp_dw_b = (const float*)d_in[10];
    const float* ksp_bn_g = (const float*)d_in[11];
    const float* ksp_bn_b = (const float*)d_in[12];
    const float* ksp_pw_w = (const float*)d_in[13];
    const float* kch_w    = (const float*)d_in[14];
    const float* lepe_w   = (const float*)d_in[15];
    const float* lepe_b   = (const float*)d_in[16];
    const float* rope_cos = (const float*)d_in[17];
    const float* rope_sin = (const float*)d_in[18];

    float* ws     = (float*)d_ws;
    float* qk     = ws;                       // 33554432 floats (128 MB)
    float* s_sp_q = qk + 33554432;            // 32768
    float* s_sp_k = s_sp_q + 32768;           // 32768
    float* sch_q  = s_sp_k + 32768;           // 4096
    float* sch_k  = sch_q + 4096;             // 4096
    float* pool_q = sch_k + 4096;             // 4096  <- zeroed region starts here
    float* pool_k = pool_q + 4096;            // 4096
    float* kmean  = pool_k + 4096;            // 4096
    float* kv     = kmean + 4096;             // 131072
    _Float16* x_hi = (_Float16*)(kv + 131072);     // 32 MB
    _Float16* x_lo = x_hi + 16777216;              // 32 MB
    _Float16* w_hi = x_lo + 16777216;              // 1 MB
    _Float16* w_lo = w_hi + 524288;                // 1 MB

    hipMemsetAsync(pool_q, 0, (size_t)(3 * 4096 + 131072) * sizeof(float), stream);

    k_split<<<16384, 256, 0, stream>>>((const float4*)x, (half4*)x_hi, (half4*)x_lo, 4194304);
    k_split<<<512, 256, 0, stream>>>((const float4*)qk_w, (half4*)w_hi, (half4*)w_lo, 131072);
    k_gemm_mfma<<<dim3(256, 8), 256, 0, stream>>>(x_hi, x_lo, w_hi, w_lo, qk_b, qk);

    k_spatial<<<dim3(2048, 2), 512, 0, stream>>>(qk,
        qsp_dw_w, qsp_dw_b, qsp_bn_g, qsp_bn_b, qsp_pw_w,
        ksp_dw_w, ksp_dw_b, ksp_bn_g, ksp_bn_b, ksp_pw_w,
        s_sp_q, s_sp_k, pool_q, pool_k);
    k_chsig<<<2048, 256, 0, stream>>>(pool_q, pool_k, qch_w, kch_w, sch_q, sch_k);
    k_kv<<<dim3(128, 8), 256, 0, stream>>>(qk, x, s_sp_k, sch_k, rope_cos, rope_sin,
                                           kv, kmean);
    k_final<<<1024, 512, 0, stream>>>(qk, x, kv, kmean, s_sp_q, sch_q,
                                      rope_cos, rope_sin, lepe_w, lepe_b, (float*)d_out);
}

// Round 3
// 491.105 us; speedup vs baseline: 1.1071x; 1.0628x over previous
//
#include <hip/hip_runtime.h>
#include <cmath>

namespace {

constexpr int CH    = 512;
constexpr int NPIX  = 4096;   // 64*64

typedef _Float16 half8 __attribute__((ext_vector_type(8)));
typedef _Float16 half4 __attribute__((ext_vector_type(4)));
typedef float    f32x4 __attribute__((ext_vector_type(4)));

__device__ __forceinline__ float sigmoidf_(float v) { return 1.0f / (1.0f + expf(-v)); }

// ======================= K0: fp32 -> (hi, lo*1024) f16 split ==============
__global__ __launch_bounds__(256) void k_split(
    const float4* __restrict__ in, half4* __restrict__ hi,
    half4* __restrict__ lo, int n4)
{
    int i = blockIdx.x * 256 + threadIdx.x;
    if (i >= n4) return;
    float4 v = in[i];
    half4 h, l;
    h[0] = (_Float16)v.x; l[0] = (_Float16)((v.x - (float)h[0]) * 1024.0f);
    h[1] = (_Float16)v.y; l[1] = (_Float16)((v.y - (float)h[1]) * 1024.0f);
    h[2] = (_Float16)v.z; l[2] = (_Float16)((v.z - (float)h[2]) * 1024.0f);
    h[3] = (_Float16)v.w; l[3] = (_Float16)((v.w - (float)h[3]) * 1024.0f);
    hi[i] = h; lo[i] = l;
}

// ======================= K1: qk = x @ qk_w^T + qk_b (split-f16 MFMA) ======
__global__ __launch_bounds__(256, 2) void k_gemm_mfma(
    const _Float16* __restrict__ Ahi, const _Float16* __restrict__ Alo,
    const _Float16* __restrict__ Bhi, const _Float16* __restrict__ Blo,
    const float* __restrict__ bias, float* __restrict__ out)
{
    __shared__ _Float16 lds[4 * 128 * 32];   // Ahi | Alo | Bhi | Blo tiles
    const int t    = threadIdx.x;
    const int wave = t >> 6;
    const int lane = t & 63;
    const int bm   = blockIdx.x;             // 0..255
    const int bn   = blockIdx.y;             // 0..7

    const _Float16* src;
    switch (wave) {
        case 0: src = Ahi + (size_t)bm * 128 * 512; break;
        case 1: src = Alo + (size_t)bm * 128 * 512; break;
        case 2: src = Bhi + (size_t)bn * 128 * 512; break;
        default: src = Blo + (size_t)bn * 128 * 512; break;
    }
    const _Float16* srcLane = src + (size_t)(lane >> 2) * 512 + (lane & 3) * 8;
    _Float16* ldsW = lds + wave * 4096;

    const int wm = wave >> 1, wn = wave & 1;
    const int mrow = lane & 15;
    const int kq   = (lane >> 4) * 8;
    const _Float16* aH = lds         + (wm * 64 + mrow) * 32 + kq;
    const _Float16* aL = lds + 4096  + (wm * 64 + mrow) * 32 + kq;
    const _Float16* bH = lds + 8192  + (wn * 64 + mrow) * 32 + kq;
    const _Float16* bL = lds + 12288 + (wn * 64 + mrow) * 32 + kq;

    f32x4 acc0[4][4], acc1[4][4];
    #pragma unroll
    for (int i = 0; i < 4; i++)
        #pragma unroll
        for (int j = 0; j < 4; j++) { acc0[i][j] = (f32x4)0.0f; acc1[i][j] = (f32x4)0.0f; }

    for (int k0 = 0; k0 < 16; k0++) {
        const _Float16* g = srcLane + k0 * 32;
        #pragma unroll
        for (int r = 0; r < 8; r++) {
            __builtin_amdgcn_global_load_lds(
                (const __attribute__((address_space(1))) void*)(g + (size_t)r * 16 * 512),
                (__attribute__((address_space(3))) void*)(ldsW + r * 512),
                16, 0, 0);
        }
        __syncthreads();

        half8 ah[4], al[4], bh[4], bl[4];
        #pragma unroll
        for (int i = 0; i < 4; i++) {
            ah[i] = *(const half8*)(aH + i * 16 * 32);
            al[i] = *(const half8*)(aL + i * 16 * 32);
            bh[i] = *(const half8*)(bH + i * 16 * 32);
            bl[i] = *(const half8*)(bL + i * 16 * 32);
        }
        #pragma unroll
        for (int i = 0; i < 4; i++)
            #pragma unroll
            for (int j = 0; j < 4; j++) {
                acc0[i][j] = __builtin_amdgcn_mfma_f32_16x16x32_f16(ah[i], bh[j], acc0[i][j], 0, 0, 0);
                acc1[i][j] = __builtin_amdgcn_mfma_f32_16x16x32_f16(ah[i], bl[j], acc1[i][j], 0, 0, 0);
                acc1[i][j] = __builtin_amdgcn_mfma_f32_16x16x32_f16(al[i], bh[j], acc1[i][j], 0, 0, 0);
            }
        __syncthreads();
    }

    const int ccol = lane & 15;
    const int crow = (lane >> 4) * 4;
    #pragma unroll
    for (int j = 0; j < 4; j++) {
        int col = bn * 128 + wn * 64 + j * 16 + ccol;
        float bv = bias[col];
        #pragma unroll
        for (int i = 0; i < 4; i++) {
            size_t row0 = (size_t)bm * 128 + wm * 64 + i * 16 + crow;
            #pragma unroll
            for (int r = 0; r < 4; r++) {
                float v = acc0[i][j][r] + acc1[i][j][r] * (1.0f / 1024.0f) + bv;
                out[(row0 + r) * 1024 + col] = v;
            }
        }
    }
}

// ======================= K2: spatial gate — sliding window, w-quartered ====
__global__ __launch_bounds__(512) void k_spatial(
    const float* __restrict__ qk,
    const float* __restrict__ dw_w_q, const float* __restrict__ dw_b_q,
    const float* __restrict__ bn_g_q, const float* __restrict__ bn_b_q,
    const float* __restrict__ pw_q,
    const float* __restrict__ dw_w_k, const float* __restrict__ dw_b_k,
    const float* __restrict__ bn_g_k, const float* __restrict__ bn_b_k,
    const float* __restrict__ pw_k,
    float* __restrict__ s_sp_q, float* __restrict__ s_sp_k,
    float* __restrict__ pool_q, float* __restrict__ pool_k)
{
    const int which = blockIdx.y;
    const int bx = blockIdx.x;            // 0..2047
    const int b  = bx >> 8;
    const int h  = (bx >> 2) & 63;
    const int w0 = (bx & 3) * 16;
    const int c  = threadIdx.x;
    const float* dw_w = which ? dw_w_k : dw_w_q;
    const float* dw_b = which ? dw_b_k : dw_b_q;
    const float* bn_g = which ? bn_g_k : bn_g_q;
    const float* bn_b = which ? bn_b_k : bn_b_q;
    const float* pw   = which ? pw_k   : pw_q;
    float*       s_sp = which ? s_sp_k : s_sp_q;
    float*       pool = which ? pool_k : pool_q;

    float w9[9];
    #pragma unroll
    for (int j = 0; j < 9; j++) w9[j] = dw_w[c * 9 + j];
    const float bconv = dw_b[c];
    const float bns   = bn_g[c] * (1.0f / sqrtf(1.00001f));
    const float bnb   = bn_b[c];
    const float pwc   = pw[c];

    __shared__ float wavepart[16][8];
    __shared__ float s_row[16];
    const int lane = c & 63, wid = c >> 6;
    const float* inb  = qk + (size_t)b * NPIX * 1024 + (which ? 512 : 0);
    const float* row0 = inb + (size_t)(h * 64) * 1024 + c;
    const float* rowm = row0 - (ptrdiff_t)64 * 1024;   // h-1 (deref-guarded)
    const float* rowp = row0 + (ptrdiff_t)64 * 1024;   // h+1
    const bool hm_ok = (h > 0), hp_ok = (h < 63);

    float x0m, x00, x0p, x1m, x10, x1p, x2m, x20, x2p;
    float cent[16];

    auto LD3 = [&](int wg, float& vm, float& v0, float& vp) {
        bool wok = (wg >= 0) && (wg < 64);
        ptrdiff_t o = (ptrdiff_t)wg * 1024;
        vm = (wok && hm_ok) ? rowm[o] : 0.0f;
        v0 =  wok           ? row0[o] : 0.0f;
        vp = (wok && hp_ok) ? rowp[o] : 0.0f;
    };

    LD3(w0 - 1, x0m, x1m, x2m);
    LD3(w0,     x00, x10, x20);

    #pragma unroll
    for (int i = 0; i < 16; i++) {
        LD3(w0 + i + 1, x0p, x1p, x2p);
        float y = bconv;
        y = fmaf(x0m, w9[0], y); y = fmaf(x00, w9[1], y); y = fmaf(x0p, w9[2], y);
        y = fmaf(x1m, w9[3], y); y = fmaf(x10, w9[4], y); y = fmaf(x1p, w9[5], y);
        y = fmaf(x2m, w9[6], y); y = fmaf(x20, w9[7], y); y = fmaf(x2p, w9[8], y);
        y = fmaxf(fmaf(y, bns, bnb), 0.0f);
        cent[i] = x10;
        float contrib = y * pwc;
        #pragma unroll
        for (int o = 32; o > 0; o >>= 1) contrib += __shfl_down(contrib, o, 64);
        if (lane == 0) wavepart[i][wid] = contrib;
        x0m = x00; x00 = x0p;
        x1m = x10; x10 = x1p;
        x2m = x20; x20 = x2p;
    }
    __syncthreads();
    if (c < 16) {
        float s = 0.0f;
        #pragma unroll
        for (int j = 0; j < 8; j++) s += wavepart[c][j];
        s = sigmoidf_(s);
        s_row[c] = s;
        s_sp[(size_t)b * NPIX + h * 64 + w0 + c] = s;
    }
    __syncthreads();
    float pacc = 0.0f;
    #pragma unroll
    for (int i = 0; i < 16; i++) pacc = fmaf(cent[i], s_row[i], pacc);
    atomicAdd(&pool[(size_t)b * CH + c], pacc);
}

// ======================= K3: channel sigmoid ===============================
__global__ __launch_bounds__(256) void k_chsig(
    const float* __restrict__ pool_q, const float* __restrict__ pool_k,
    const float* __restrict__ qch_w,  const float* __restrict__ kch_w,
    float* __restrict__ sch_q, float* __restrict__ sch_k)
{
    int id    = blockIdx.x;           // 0..2047
    int which = id >> 10;
    int rem   = id & 1023;
    int b     = rem >> 7;             // 0..7
    int og    = rem & 127;            // 0..127
    int wid   = threadIdx.x >> 6, lane = threadIdx.x & 63;
    int o     = og * 4 + wid;
    const float* pool = which ? pool_k : pool_q;
    const float* Wt   = which ? kch_w  : qch_w;
    float s = 0.0f;
    for (int cc = lane; cc < CH; cc += 64) s = fmaf(pool[b * CH + cc], Wt[o * CH + cc], s);
    #pragma unroll
    for (int off = 32; off > 0; off >>= 1) s += __shfl_down(s, off, 64);
    if (lane == 0)
        (which ? sch_k : sch_q)[b * CH + o] = sigmoidf_(s * (1.0f / 4096.0f));
}

// ======================= K4: kv accumulate, rope(k) fused in-register ======
__global__ __launch_bounds__(256) void k_kv(
    const float* __restrict__ qk, const float* __restrict__ x,
    const float* __restrict__ s_sp_k, const float* __restrict__ sch_k,
    const float* __restrict__ cosT,   const float* __restrict__ sinT,
    float* __restrict__ kv, float* __restrict__ kmean)
{
    const int bh = blockIdx.x;      // 0..127
    const int b  = bh >> 4, hh = bh & 15;
    const int n0 = blockIdx.y * 512;
    __shared__ float kt[32][33];
    __shared__ float vt[32][33];
    const int t  = threadIdx.x;
    const int e  = t & 31, d0 = (t >> 5) * 4;
    const int nn  = t >> 3;
    const int cc4 = (t & 7) * 4;
    const int cg  = hh * 32 + cc4;          // global channel of lane's quad
    const int kidx = cg >> 1;               // rope pair index (even)

    const float sch0 = sch_k[b * CH + cg + 0];
    const float sch1 = sch_k[b * CH + cg + 1];
    const float sch2 = sch_k[b * CH + cg + 2];
    const float sch3 = sch_k[b * CH + cg + 3];

    float km0 = 0.f, km1 = 0.f, km2 = 0.f, km3 = 0.f;
    float acc[4] = {0.f, 0.f, 0.f, 0.f};
    for (int s = 0; s < 512; s += 32) {
        const int n = n0 + s + nn;
        size_t rowbase = (size_t)(b * NPIX + n);
        float4 kvv = *(const float4*)(qk + rowbase * 1024 + 512 + cg);
        const float ssp = s_sp_k[(size_t)b * NPIX + n];
        float g0 = kvv.x * ssp * sch0;
        float g1 = kvv.y * ssp * sch1;
        float g2 = kvv.z * ssp * sch2;
        float g3 = kvv.w * ssp * sch3;
        float e0 = g0 > 0.0f ? g0 + 1.0f : expf(g0);
        float e1 = g1 > 0.0f ? g1 + 1.0f : expf(g1);
        float e2 = g2 > 0.0f ? g2 + 1.0f : expf(g2);
        float e3 = g3 > 0.0f ? g3 + 1.0f : expf(g3);
        const float cs0 = cosT[(size_t)n * 256 + kidx];
        const float sn0 = sinT[(size_t)n * 256 + kidx];
        const float cs1 = cosT[(size_t)n * 256 + kidx + 1];
        const float sn1 = sinT[(size_t)n * 256 + kidx + 1];
        float r0 = fmaf(cs0, e0, -(sn0 * e1));
        float r1 = fmaf(sn0, e0,   cs0 * e1);
        float r2 = fmaf(cs1, e2, -(sn1 * e3));
        float r3 = fmaf(sn1, e2,   cs1 * e3);
        kt[nn][cc4] = r0; kt[nn][cc4+1] = r1; kt[nn][cc4+2] = r2; kt[nn][cc4+3] = r3;
        km0 += r0; km1 += r1; km2 += r2; km3 += r3;
        float4 vv  = *(const float4*)(x + rowbase * 512 + cg);
        vt[nn][cc4] = vv.x; vt[nn][cc4+1] = vv.y; vt[nn][cc4+2] = vv.z; vt[nn][cc4+3] = vv.w;
        __syncthreads();
        #pragma unroll
        for (int q = 0; q < 32; q++) {
            float vq = vt[q][e];
            acc[0] = fmaf(kt[q][d0    ], vq, acc[0]);
            acc[1] = fmaf(kt[q][d0 + 1], vq, acc[1]);
            acc[2] = fmaf(kt[q][d0 + 2], vq, acc[2]);
            acc[3] = fmaf(kt[q][d0 + 3], vq, acc[3]);
        }
        __syncthreads();
    }
    #pragma unroll
    for (int i = 0; i < 4; i++)
        atomicAdd(&kv[((size_t)bh * 32 + d0 + i) * 32 + e], acc[i]);
    atomicAdd(&kmean[(size_t)b * CH + cg + 0], km0);
    atomicAdd(&kmean[(size_t)b * CH + cg + 1], km1);
    atomicAdd(&kmean[(size_t)b * CH + cg + 2], km2);
    atomicAdd(&kmean[(size_t)b * CH + cg + 3], km3);
}

// ======================= K5: out = (q_r @ kv)*z + lepe — rope(q) fused =====
// num loop: qv staged in per-head LDS row (padded to 160B: 16B-aligned,
// head-pair rows land on distinct banks), read back as 8x ds_read_b128
// uniform-address broadcasts instead of 32x ds_bpermute. 4 independent
// accumulators break the fma chain; depth-1 prefetch of strided scalars.
__global__ __launch_bounds__(512) void k_final(
    const float* __restrict__ qk, const float* __restrict__ x,
    const float* __restrict__ kvbuf, const float* __restrict__ kmean,
    const float* __restrict__ s_sp_q, const float* __restrict__ sch_q,
    const float* __restrict__ cosT,   const float* __restrict__ sinT,
    const float* __restrict__ lepe_w, const float* __restrict__ lepe_b,
    float* __restrict__ out)
{
    const int bx = blockIdx.x;            // 0..1023
    const int b  = bx >> 7;
    const int h  = (bx >> 1) & 63;
    const int w0 = (bx & 1) * 32;
    const int c  = threadIdx.x;
    const int e  = c & 31;
    const int head = c >> 5;
    const int kidx = c >> 1;
    const int odd  = c & 1;

    __shared__ float qv_lds[16][40];      // 160B rows: 16B aligned, bank-spread

    float kvreg[32];
    #pragma unroll
    for (int d = 0; d < 32; d++)
        kvreg[d] = kvbuf[((size_t)b * 16 + head) * 1024 + d * 32 + e] * (1.0f / 4096.0f);
    const float km = kmean[(size_t)b * CH + c] * (1.0f / 4096.0f);
    const float schc = sch_q[(size_t)b * CH + c];
    float w9[9];
    #pragma unroll
    for (int j = 0; j < 9; j++) w9[j] = lepe_w[c * 9 + j];
    const float lb = lepe_b[c];

    const float* xr0 = x + ((size_t)b * NPIX + h * 64) * 512 + c;
    const float* xrm = xr0 - (ptrdiff_t)64 * 512;
    const float* xrp = xr0 + (ptrdiff_t)64 * 512;
    const bool hm_ok = (h > 0), hp_ok = (h < 63);
    const float* qkb = qk + ((size_t)b * NPIX + h * 64) * 1024 + c;
    const float* ssb = s_sp_q + (size_t)b * NPIX + h * 64;
    const float* csb = cosT + (size_t)(h * 64) * 256 + kidx;
    const float* snb = sinT + (size_t)(h * 64) * 256 + kidx;
    float* outb = out + ((size_t)b * NPIX + h * 64) * 512 + c;

    float x0m, x00, x0p, x1m, x10, x1p, x2m, x20, x2p;
    auto LD3 = [&](int wg, float& vm, float& v0, float& vp) {
        bool wok = (wg >= 0) && (wg < 64);
        ptrdiff_t o = (ptrdiff_t)wg * 512;
        vm = (wok && hm_ok) ? xrm[o] : 0.0f;
        v0 =  wok           ? xr0[o] : 0.0f;
        vp = (wok && hp_ok) ? xrp[o] : 0.0f;
    };
    LD3(w0 - 1, x0m, x1m, x2m);
    LD3(w0,     x00, x10, x20);

    // depth-1 prefetch of per-pixel scalars
    float qraw = qkb[(size_t)w0 * 1024];
    float ssp  = ssb[w0];
    float cs   = csb[(size_t)w0 * 256];
    float sn   = snb[(size_t)w0 * 256];

    for (int i = 0; i < 32; i++) {
        const int wg = w0 + i;
        float x0p_, x1p_, x2p_;
        LD3(wg + 1, x0p_, x1p_, x2p_);
        x0p = x0p_; x1p = x1p_; x2p = x2p_;

        float qraw_n = 0.0f, ssp_n = 0.0f, cs_n = 0.0f, sn_n = 0.0f;
        if (i < 31) {
            qraw_n = qkb[(size_t)(wg + 1) * 1024];
            ssp_n  = ssb[wg + 1];
            cs_n   = csb[(size_t)(wg + 1) * 256];
            sn_n   = snb[(size_t)(wg + 1) * 256];
        }

        // --- fused gate + elu + rope for q ---
        float g    = qraw * ssp * schc;
        float eV   = g > 0.0f ? g + 1.0f : expf(g);
        float part = __shfl_xor(eV, 1, 64);
        float qv   = odd ? fmaf(sn, part, cs * eV) : fmaf(cs, eV, -(sn * part));

        qv_lds[head][e] = qv;

        float den = qv * km;
        #pragma unroll
        for (int off = 16; off > 0; off >>= 1) den += __shfl_xor(den, off, 32);
        float z = 1.0f / (den + 1e-6f);

        float num0 = 0.0f, num1 = 0.0f, num2 = 0.0f, num3 = 0.0f;
        #pragma unroll
        for (int dq = 0; dq < 8; dq++) {
            float4 q4 = *(const float4*)&qv_lds[head][dq * 4];
            num0 = fmaf(q4.x, kvreg[dq * 4 + 0], num0);
            num1 = fmaf(q4.y, kvreg[dq * 4 + 1], num1);
            num2 = fmaf(q4.z, kvreg[dq * 4 + 2], num2);
            num3 = fmaf(q4.w, kvreg[dq * 4 + 3], num3);
        }
        float num = (num0 + num1) + (num2 + num3);

        float lp = lb;
        lp = fmaf(x0m, w9[0], lp); lp = fmaf(x00, w9[1], lp); lp = fmaf(x0p, w9[2], lp);
        lp = fmaf(x1m, w9[3], lp); lp = fmaf(x10, w9[4], lp); lp = fmaf(x1p, w9[5], lp);
        lp = fmaf(x2m, w9[6], lp); lp = fmaf(x20, w9[7], lp);

        outb[(size_t)wg * 512] = fmaf(num, z, fmaf(x2p, w9[8], lp));

        qraw = qraw_n; ssp = ssp_n; cs = cs_n; sn = sn_n;
        x0m = x00; x00 = x0p;
        x1m = x10; x10 = x1p;
        x2m = x20; x20 = x2p;
    }
}

} // namespace

extern "C" void kernel_launch(void* const* d_in, const int* in_sizes, int n_in,
                              void* d_out, int out_size, void* d_ws, size_t ws_size,
                              hipStream_t stream)
{
    (void)in_sizes; (void)n_in; (void)out_size; (void)ws_size;
    const float* x        = (const float*)d_in[0];
    const float* qk_w     = (const float*)d_in[1];
    const float* qk_b     = (const float*)d_in[2];
    const float* qsp_dw_w = (const float*)d_in[3];
    const float* qsp_dw_b = (const float*)d_in[4];
    const float* qsp_bn_g = (const float*)d_in[5];
    const float* qsp_bn_b = (const float*)d_in[6];
    const float* qsp_pw_w = (const float*)d_in[7];
    const float* qch_w    = (const float*)d_in[8];
    const float* ksp_dw_w = (const float*)d_in[9];
    const float* ksp_dw_b = (const float*)d_in[10];
    const float* ksp_bn_g = (const float*)d_in[11];
    const float* ksp_bn_b = (const float*)d_in[12];
    const float* ksp_pw_w = (const float*)d_in[13];
    const float* kch_w    = (const float*)d_in[14];
    const float* lepe_w   = (const float*)d_in[15];
    const float* lepe_b   = (const float*)d_in[16];
    const float* rope_cos = (const float*)d_in[17];
    const float* rope_sin = (const float*)d_in[18];

    float* ws     = (float*)d_ws;
    float* qk     = ws;                       // 33554432 floats (128 MB)
    float* s_sp_q = qk + 33554432;            // 32768
    float* s_sp_k = s_sp_q + 32768;           // 32768
    float* sch_q  = s_sp_k + 32768;           // 4096
    float* sch_k  = sch_q + 4096;             // 4096
    float* pool_q = sch_k + 4096;             // 4096  <- zeroed region starts here
    float* pool_k = pool_q + 4096;            // 4096
    float* kmean  = pool_k + 4096;            // 4096
    float* kv     = kmean + 4096;             // 131072
    _Float16* x_hi = (_Float16*)(kv + 131072);     // 32 MB
    _Float16* x_lo = x_hi + 16777216;              // 32 MB
    _Float16* w_hi = x_lo + 16777216;              // 1 MB
    _Float16* w_lo = w_hi + 524288;                // 1 MB

    hipMemsetAsync(pool_q, 0, (size_t)(3 * 4096 + 131072) * sizeof(float), stream);

    k_split<<<16384, 256, 0, stream>>>((const float4*)x, (half4*)x_hi, (half4*)x_lo, 4194304);
    k_split<<<512, 256, 0, stream>>>((const float4*)qk_w, (half4*)w_hi, (half4*)w_lo, 131072);
    k_gemm_mfma<<<dim3(256, 8), 256, 0, stream>>>(x_hi, x_lo, w_hi, w_lo, qk_b, qk);

    k_spatial<<<dim3(2048, 2), 512, 0, stream>>>(qk,
        qsp_dw_w, qsp_dw_b, qsp_bn_g, qsp_bn_b, qsp_pw_w,
        ksp_dw_w, ksp_dw_b, ksp_bn_g, ksp_bn_b, ksp_pw_w,
        s_sp_q, s_sp_k, pool_q, pool_k);
    k_chsig<<<2048, 256, 0, stream>>>(pool_q, pool_k, qch_w, kch_w, sch_q, sch_k);
    k_kv<<<dim3(128, 8), 256, 0, stream>>>(qk, x, s_sp_k, sch_k, rope_cos, rope_sin,
                                           kv, kmean);
    k_final<<<1024, 512, 0, stream>>>(qk, x, kv, kmean, s_sp_q, sch_q,
                                      rope_cos, rope_sin, lepe_w, lepe_b, (float*)d_out);
}

// Round 5
// 467.480 us; speedup vs baseline: 1.1631x; 1.0505x over previous
//
#include <hip/hip_runtime.h>
#include <cmath>

namespace {

constexpr int CH    = 512;
constexpr int NPIX  = 4096;   // 64*64

typedef _Float16 half8 __attribute__((ext_vector_type(8)));
typedef _Float16 half4 __attribute__((ext_vector_type(4)));
typedef float    f32x4 __attribute__((ext_vector_type(4)));

__device__ __forceinline__ float sigmoidf_(float v) { return 1.0f / (1.0f + expf(-v)); }

// ======================= K0: fp32 -> (hi, lo*1024) f16 split ==============
__global__ __launch_bounds__(256) void k_split(
    const float4* __restrict__ in, half4* __restrict__ hi,
    half4* __restrict__ lo, int n4)
{
    int i = blockIdx.x * 256 + threadIdx.x;
    if (i >= n4) return;
    float4 v = in[i];
    half4 h, l;
    h[0] = (_Float16)v.x; l[0] = (_Float16)((v.x - (float)h[0]) * 1024.0f);
    h[1] = (_Float16)v.y; l[1] = (_Float16)((v.y - (float)h[1]) * 1024.0f);
    h[2] = (_Float16)v.z; l[2] = (_Float16)((v.z - (float)h[2]) * 1024.0f);
    h[3] = (_Float16)v.w; l[3] = (_Float16)((v.w - (float)h[3]) * 1024.0f);
    hi[i] = h; lo[i] = l;
}

// ======================= K1: qk = x @ qk_w^T + qk_b (split-f16 MFMA) ======
__global__ __launch_bounds__(256, 2) void k_gemm_mfma(
    const _Float16* __restrict__ Ahi, const _Float16* __restrict__ Alo,
    const _Float16* __restrict__ Bhi, const _Float16* __restrict__ Blo,
    const float* __restrict__ bias, float* __restrict__ out)
{
    __shared__ _Float16 lds[4 * 128 * 32];   // Ahi | Alo | Bhi | Blo tiles
    const int t    = threadIdx.x;
    const int wave = t >> 6;
    const int lane = t & 63;
    const int bm   = blockIdx.x;             // 0..255
    const int bn   = blockIdx.y;             // 0..7

    const _Float16* src;
    switch (wave) {
        case 0: src = Ahi + (size_t)bm * 128 * 512; break;
        case 1: src = Alo + (size_t)bm * 128 * 512; break;
        case 2: src = Bhi + (size_t)bn * 128 * 512; break;
        default: src = Blo + (size_t)bn * 128 * 512; break;
    }
    const _Float16* srcLane = src + (size_t)(lane >> 2) * 512 + (lane & 3) * 8;
    _Float16* ldsW = lds + wave * 4096;

    const int wm = wave >> 1, wn = wave & 1;
    const int mrow = lane & 15;
    const int kq   = (lane >> 4) * 8;
    const _Float16* aH = lds         + (wm * 64 + mrow) * 32 + kq;
    const _Float16* aL = lds + 4096  + (wm * 64 + mrow) * 32 + kq;
    const _Float16* bH = lds + 8192  + (wn * 64 + mrow) * 32 + kq;
    const _Float16* bL = lds + 12288 + (wn * 64 + mrow) * 32 + kq;

    f32x4 acc0[4][4], acc1[4][4];
    #pragma unroll
    for (int i = 0; i < 4; i++)
        #pragma unroll
        for (int j = 0; j < 4; j++) { acc0[i][j] = (f32x4)0.0f; acc1[i][j] = (f32x4)0.0f; }

    for (int k0 = 0; k0 < 16; k0++) {
        const _Float16* g = srcLane + k0 * 32;
        #pragma unroll
        for (int r = 0; r < 8; r++) {
            __builtin_amdgcn_global_load_lds(
                (const __attribute__((address_space(1))) void*)(g + (size_t)r * 16 * 512),
                (__attribute__((address_space(3))) void*)(ldsW + r * 512),
                16, 0, 0);
        }
        __syncthreads();

        half8 ah[4], al[4], bh[4], bl[4];
        #pragma unroll
        for (int i = 0; i < 4; i++) {
            ah[i] = *(const half8*)(aH + i * 16 * 32);
            al[i] = *(const half8*)(aL + i * 16 * 32);
            bh[i] = *(const half8*)(bH + i * 16 * 32);
            bl[i] = *(const half8*)(bL + i * 16 * 32);
        }
        #pragma unroll
        for (int i = 0; i < 4; i++)
            #pragma unroll
            for (int j = 0; j < 4; j++) {
                acc0[i][j] = __builtin_amdgcn_mfma_f32_16x16x32_f16(ah[i], bh[j], acc0[i][j], 0, 0, 0);
                acc1[i][j] = __builtin_amdgcn_mfma_f32_16x16x32_f16(ah[i], bl[j], acc1[i][j], 0, 0, 0);
                acc1[i][j] = __builtin_amdgcn_mfma_f32_16x16x32_f16(al[i], bh[j], acc1[i][j], 0, 0, 0);
            }
        __syncthreads();
    }

    const int ccol = lane & 15;
    const int crow = (lane >> 4) * 4;
    #pragma unroll
    for (int j = 0; j < 4; j++) {
        int col = bn * 128 + wn * 64 + j * 16 + ccol;
        float bv = bias[col];
        #pragma unroll
        for (int i = 0; i < 4; i++) {
            size_t row0 = (size_t)bm * 128 + wm * 64 + i * 16 + crow;
            #pragma unroll
            for (int r = 0; r < 4; r++) {
                float v = acc0[i][j][r] + acc1[i][j][r] * (1.0f / 1024.0f) + bv;
                out[(row0 + r) * 1024 + col] = v;
            }
        }
    }
}

// ======================= K2: spatial gate — sliding window, w-quartered ====
// Per-pixel channel reduction via LDS transpose + one cooperative reduce
// (replaces 16 serialized 6-step shfl chains per thread).
__global__ __launch_bounds__(512) void k_spatial(
    const float* __restrict__ qk,
    const float* __restrict__ dw_w_q, const float* __restrict__ dw_b_q,
    const float* __restrict__ bn_g_q, const float* __restrict__ bn_b_q,
    const float* __restrict__ pw_q,
    const float* __restrict__ dw_w_k, const float* __restrict__ dw_b_k,
    const float* __restrict__ bn_g_k, const float* __restrict__ bn_b_k,
    const float* __restrict__ pw_k,
    float* __restrict__ s_sp_q, float* __restrict__ s_sp_k,
    float* __restrict__ pool_q, float* __restrict__ pool_k)
{
    const int which = blockIdx.y;
    const int bx = blockIdx.x;            // 0..2047
    const int b  = bx >> 8;
    const int h  = (bx >> 2) & 63;
    const int w0 = (bx & 3) * 16;
    const int c  = threadIdx.x;
    const float* dw_w = which ? dw_w_k : dw_w_q;
    const float* dw_b = which ? dw_b_k : dw_b_q;
    const float* bn_g = which ? bn_g_k : bn_g_q;
    const float* bn_b = which ? bn_b_k : bn_b_q;
    const float* pw   = which ? pw_k   : pw_q;
    float*       s_sp = which ? s_sp_k : s_sp_q;
    float*       pool = which ? pool_k : pool_q;

    float w9[9];
    #pragma unroll
    for (int j = 0; j < 9; j++) w9[j] = dw_w[c * 9 + j];
    const float bconv = dw_b[c];
    const float bns   = bn_g[c] * (1.0f / sqrtf(1.00001f));
    const float bnb   = bn_b[c];
    const float pwc   = pw[c];

    __shared__ float part[512][17];       // stride-17: conflict-free both passes
    __shared__ float s_row[16];
    const float* inb  = qk + (size_t)b * NPIX * 1024 + (which ? 512 : 0);
    const float* row0 = inb + (size_t)(h * 64) * 1024 + c;
    const float* rowm = row0 - (ptrdiff_t)64 * 1024;   // h-1 (deref-guarded)
    const float* rowp = row0 + (ptrdiff_t)64 * 1024;   // h+1
    const bool hm_ok = (h > 0), hp_ok = (h < 63);

    float x0m, x00, x0p, x1m, x10, x1p, x2m, x20, x2p;
    float cent[16];

    auto LD3 = [&](int wg, float& vm, float& v0, float& vp) {
        bool wok = (wg >= 0) && (wg < 64);
        ptrdiff_t o = (ptrdiff_t)wg * 1024;
        vm = (wok && hm_ok) ? rowm[o] : 0.0f;
        v0 =  wok           ? row0[o] : 0.0f;
        vp = (wok && hp_ok) ? rowp[o] : 0.0f;
    };

    LD3(w0 - 1, x0m, x1m, x2m);
    LD3(w0,     x00, x10, x20);

    #pragma unroll
    for (int i = 0; i < 16; i++) {
        LD3(w0 + i + 1, x0p, x1p, x2p);
        float y = bconv;
        y = fmaf(x0m, w9[0], y); y = fmaf(x00, w9[1], y); y = fmaf(x0p, w9[2], y);
        y = fmaf(x1m, w9[3], y); y = fmaf(x10, w9[4], y); y = fmaf(x1p, w9[5], y);
        y = fmaf(x2m, w9[6], y); y = fmaf(x2p, w9[8], fmaf(x20, w9[7], y));
        y = fmaxf(fmaf(y, bns, bnb), 0.0f);
        cent[i] = x10;
        part[c][i] = y * pwc;
        x0m = x00; x00 = x0p;
        x1m = x10; x10 = x1p;
        x2m = x20; x20 = x2p;
    }
    __syncthreads();
    {
        const int p = c >> 5;             // pixel 0..15
        const int j = c & 31;             // reducer lane within 32-group
        float s = 0.0f;
        #pragma unroll
        for (int m = 0; m < 16; m++) s += part[j + 32 * m][p];
        #pragma unroll
        for (int off = 16; off > 0; off >>= 1) s += __shfl_xor(s, off, 32);
        if (j == 0) {
            float sg = sigmoidf_(s);
            s_row[p] = sg;
            s_sp[(size_t)b * NPIX + h * 64 + w0 + p] = sg;
        }
    }
    __syncthreads();
    float pacc = 0.0f;
    #pragma unroll
    for (int i = 0; i < 16; i++) pacc = fmaf(cent[i], s_row[i], pacc);
    atomicAdd(&pool[(size_t)b * CH + c], pacc);
}

// ======================= K3: channel sigmoid ===============================
__global__ __launch_bounds__(256) void k_chsig(
    const float* __restrict__ pool_q, const float* __restrict__ pool_k,
    const float* __restrict__ qch_w,  const float* __restrict__ kch_w,
    float* __restrict__ sch_q, float* __restrict__ sch_k)
{
    int id    = blockIdx.x;           // 0..2047
    int which = id >> 10;
    int rem   = id & 1023;
    int b     = rem >> 7;             // 0..7
    int og    = rem & 127;            // 0..127
    int wid   = threadIdx.x >> 6, lane = threadIdx.x & 63;
    int o     = og * 4 + wid;
    const float* pool = which ? pool_k : pool_q;
    const float* Wt   = which ? kch_w  : qch_w;
    float s = 0.0f;
    for (int cc = lane; cc < CH; cc += 64) s = fmaf(pool[b * CH + cc], Wt[o * CH + cc], s);
    #pragma unroll
    for (int off = 32; off > 0; off >>= 1) s += __shfl_down(s, off, 64);
    if (lane == 0)
        (which ? sch_k : sch_q)[b * CH + o] = sigmoidf_(s * (1.0f / 4096.0f));
}

// ======================= K4: kv accumulate, rope(k) fused in-register ======
__global__ __launch_bounds__(256) void k_kv(
    const float* __restrict__ qk, const float* __restrict__ x,
    const float* __restrict__ s_sp_k, const float* __restrict__ sch_k,
    const float* __restrict__ cosT,   const float* __restrict__ sinT,
    float* __restrict__ kv, float* __restrict__ kmean)
{
    const int bh = blockIdx.x;      // 0..127
    const int b  = bh >> 4, hh = bh & 15;
    const int n0 = blockIdx.y * 512;
    __shared__ float kt[32][33];
    __shared__ float vt[32][33];
    const int t  = threadIdx.x;
    const int e  = t & 31, d0 = (t >> 5) * 4;
    const int nn  = t >> 3;
    const int cc4 = (t & 7) * 4;
    const int cg  = hh * 32 + cc4;          // global channel of lane's quad
    const int kidx = cg >> 1;               // rope pair index (even)

    const float sch0 = sch_k[b * CH + cg + 0];
    const float sch1 = sch_k[b * CH + cg + 1];
    const float sch2 = sch_k[b * CH + cg + 2];
    const float sch3 = sch_k[b * CH + cg + 3];

    float km0 = 0.f, km1 = 0.f, km2 = 0.f, km3 = 0.f;
    float acc[4] = {0.f, 0.f, 0.f, 0.f};
    for (int s = 0; s < 512; s += 32) {
        const int n = n0 + s + nn;
        size_t rowbase = (size_t)(b * NPIX + n);
        float4 kvv = *(const float4*)(qk + rowbase * 1024 + 512 + cg);
        const float ssp = s_sp_k[(size_t)b * NPIX + n];
        float g0 = kvv.x * ssp * sch0;
        float g1 = kvv.y * ssp * sch1;
        float g2 = kvv.z * ssp * sch2;
        float g3 = kvv.w * ssp * sch3;
        float e0 = g0 > 0.0f ? g0 + 1.0f : expf(g0);
        float e1 = g1 > 0.0f ? g1 + 1.0f : expf(g1);
        float e2 = g2 > 0.0f ? g2 + 1.0f : expf(g2);
        float e3 = g3 > 0.0f ? g3 + 1.0f : expf(g3);
        const float cs0 = cosT[(size_t)n * 256 + kidx];
        const float sn0 = sinT[(size_t)n * 256 + kidx];
        const float cs1 = cosT[(size_t)n * 256 + kidx + 1];
        const float sn1 = sinT[(size_t)n * 256 + kidx + 1];
        float r0 = fmaf(cs0, e0, -(sn0 * e1));
        float r1 = fmaf(sn0, e0,   cs0 * e1);
        float r2 = fmaf(cs1, e2, -(sn1 * e3));
        float r3 = fmaf(sn1, e2,   cs1 * e3);
        kt[nn][cc4] = r0; kt[nn][cc4+1] = r1; kt[nn][cc4+2] = r2; kt[nn][cc4+3] = r3;
        km0 += r0; km1 += r1; km2 += r2; km3 += r3;
        float4 vv  = *(const float4*)(x + rowbase * 512 + cg);
        vt[nn][cc4] = vv.x; vt[nn][cc4+1] = vv.y; vt[nn][cc4+2] = vv.z; vt[nn][cc4+3] = vv.w;
        __syncthreads();
        #pragma unroll
        for (int q = 0; q < 32; q++) {
            float vq = vt[q][e];
            acc[0] = fmaf(kt[q][d0    ], vq, acc[0]);
            acc[1] = fmaf(kt[q][d0 + 1], vq, acc[1]);
            acc[2] = fmaf(kt[q][d0 + 2], vq, acc[2]);
            acc[3] = fmaf(kt[q][d0 + 3], vq, acc[3]);
        }
        __syncthreads();
    }
    #pragma unroll
    for (int i = 0; i < 4; i++)
        atomicAdd(&kv[((size_t)bh * 32 + d0 + i) * 32 + e], acc[i]);
    atomicAdd(&kmean[(size_t)b * CH + cg + 0], km0);
    atomicAdd(&kmean[(size_t)b * CH + cg + 1], km1);
    atomicAdd(&kmean[(size_t)b * CH + cg + 2], km2);
    atomicAdd(&kmean[(size_t)b * CH + cg + 3], km3);
}

// ======================= K5: out = (q_r @ kv)*z + lepe — rope(q) fused =====
// num AND den both computed from the same 8x ds_read_b128 qv broadcasts
// (kmreg mirrors kvreg) — no cross-lane den reduction at all.
__global__ __launch_bounds__(512) void k_final(
    const float* __restrict__ qk, const float* __restrict__ x,
    const float* __restrict__ kvbuf, const float* __restrict__ kmean,
    const float* __restrict__ s_sp_q, const float* __restrict__ sch_q,
    const float* __restrict__ cosT,   const float* __restrict__ sinT,
    const float* __restrict__ lepe_w, const float* __restrict__ lepe_b,
    float* __restrict__ out)
{
    const int bx = blockIdx.x;            // 0..1023
    const int b  = bx >> 7;
    const int h  = (bx >> 1) & 63;
    const int w0 = (bx & 1) * 32;
    const int c  = threadIdx.x;
    const int e  = c & 31;
    const int head = c >> 5;
    const int kidx = c >> 1;
    const int odd  = c & 1;

    __shared__ float qv_lds[16][40];      // 160B rows: 16B aligned, bank-spread

    float kvreg[32], kmreg[32];
    #pragma unroll
    for (int d = 0; d < 32; d++)
        kvreg[d] = kvbuf[((size_t)b * 16 + head) * 1024 + d * 32 + e] * (1.0f / 4096.0f);
    #pragma unroll
    for (int d = 0; d < 32; d++)
        kmreg[d] = kmean[(size_t)b * CH + head * 32 + d] * (1.0f / 4096.0f);
    const float schc = sch_q[(size_t)b * CH + c];
    float w9[9];
    #pragma unroll
    for (int j = 0; j < 9; j++) w9[j] = lepe_w[c * 9 + j];
    const float lb = lepe_b[c];

    const float* xr0 = x + ((size_t)b * NPIX + h * 64) * 512 + c;
    const float* xrm = xr0 - (ptrdiff_t)64 * 512;
    const float* xrp = xr0 + (ptrdiff_t)64 * 512;
    const bool hm_ok = (h > 0), hp_ok = (h < 63);
    const float* qkb = qk + ((size_t)b * NPIX + h * 64) * 1024 + c;
    const float* ssb = s_sp_q + (size_t)b * NPIX + h * 64;
    const float* csb = cosT + (size_t)(h * 64) * 256 + kidx;
    const float* snb = sinT + (size_t)(h * 64) * 256 + kidx;
    float* outb = out + ((size_t)b * NPIX + h * 64) * 512 + c;

    float x0m, x00, x0p, x1m, x10, x1p, x2m, x20, x2p;
    auto LD3 = [&](int wg, float& vm, float& v0, float& vp) {
        bool wok = (wg >= 0) && (wg < 64);
        ptrdiff_t o = (ptrdiff_t)wg * 512;
        vm = (wok && hm_ok) ? xrm[o] : 0.0f;
        v0 =  wok           ? xr0[o] : 0.0f;
        vp = (wok && hp_ok) ? xrp[o] : 0.0f;
    };
    LD3(w0 - 1, x0m, x1m, x2m);
    LD3(w0,     x00, x10, x20);

    // depth-1 prefetch of per-pixel scalars
    float qraw = qkb[(size_t)w0 * 1024];
    float ssp  = ssb[w0];
    float cs   = csb[(size_t)w0 * 256];
    float sn   = snb[(size_t)w0 * 256];

    for (int i = 0; i < 32; i++) {
        const int wg = w0 + i;
        float x0p_, x1p_, x2p_;
        LD3(wg + 1, x0p_, x1p_, x2p_);
        x0p = x0p_; x1p = x1p_; x2p = x2p_;

        float qraw_n = 0.0f, ssp_n = 0.0f, cs_n = 0.0f, sn_n = 0.0f;
        if (i < 31) {
            qraw_n = qkb[(size_t)(wg + 1) * 1024];
            ssp_n  = ssb[wg + 1];
            cs_n   = csb[(size_t)(wg + 1) * 256];
            sn_n   = snb[(size_t)(wg + 1) * 256];
        }

        // --- fused gate + elu + rope for q ---
        float g    = qraw * ssp * schc;
        float eV   = g > 0.0f ? g + 1.0f : expf(g);
        float part = __shfl_xor(eV, 1, 64);
        float qv   = odd ? fmaf(sn, part, cs * eV) : fmaf(cs, eV, -(sn * part));

        qv_lds[head][e] = qv;

        float num0 = 0.0f, num1 = 0.0f, num2 = 0.0f, num3 = 0.0f;
        float den0 = 0.0f, den1 = 0.0f, den2 = 0.0f, den3 = 0.0f;
        #pragma unroll
        for (int dq = 0; dq < 8; dq++) {
            float4 q4 = *(const float4*)&qv_lds[head][dq * 4];
            num0 = fmaf(q4.x, kvreg[dq * 4 + 0], num0);
            num1 = fmaf(q4.y, kvreg[dq * 4 + 1], num1);
            num2 = fmaf(q4.z, kvreg[dq * 4 + 2], num2);
            num3 = fmaf(q4.w, kvreg[dq * 4 + 3], num3);
            den0 = fmaf(q4.x, kmreg[dq * 4 + 0], den0);
            den1 = fmaf(q4.y, kmreg[dq * 4 + 1], den1);
            den2 = fmaf(q4.z, kmreg[dq * 4 + 2], den2);
            den3 = fmaf(q4.w, kmreg[dq * 4 + 3], den3);
        }
        float num = (num0 + num1) + (num2 + num3);
        float den = (den0 + den1) + (den2 + den3);
        float z = 1.0f / (den + 1e-6f);

        float lp = lb;
        lp = fmaf(x0m, w9[0], lp); lp = fmaf(x00, w9[1], lp); lp = fmaf(x0p, w9[2], lp);
        lp = fmaf(x1m, w9[3], lp); lp = fmaf(x10, w9[4], lp); lp = fmaf(x1p, w9[5], lp);
        lp = fmaf(x2m, w9[6], lp); lp = fmaf(x20, w9[7], lp);

        outb[(size_t)wg * 512] = fmaf(num, z, fmaf(x2p, w9[8], lp));

        qraw = qraw_n; ssp = ssp_n; cs = cs_n; sn = sn_n;
        x0m = x00; x00 = x0p;
        x1m = x10; x10 = x1p;
        x2m = x20; x20 = x2p;
    }
}

} // namespace

extern "C" void kernel_launch(void* const* d_in, const int* in_sizes, int n_in,
                              void* d_out, int out_size, void* d_ws, size_t ws_size,
                              hipStream_t stream)
{
    (void)in_sizes; (void)n_in; (void)out_size; (void)ws_size;
    const float* x        = (const float*)d_in[0];
    const float* qk_w     = (const float*)d_in[1];
    const float* qk_b     = (const float*)d_in[2];
    const float* qsp_dw_w = (const float*)d_in[3];
    const float* qsp_dw_b = (const float*)d_in[4];
    const float* qsp_bn_g = (const float*)d_in[5];
    const float* qsp_bn_b = (const float*)d_in[6];
    const float* qsp_pw_w = (const float*)d_in[7];
    const float* qch_w    = (const float*)d_in[8];
    const float* ksp_dw_w = (const float*)d_in[9];
    const float* ksp_dw_b = (const float*)d_in[10];
    const float* ksp_bn_g = (const float*)d_in[11];
    const float* ksp_bn_b = (const float*)d_in[12];
    const float* ksp_pw_w = (const float*)d_in[13];
    const float* kch_w    = (const float*)d_in[14];
    const float* lepe_w   = (const float*)d_in[15];
    const float* lepe_b   = (const float*)d_in[16];
    const float* rope_cos = (const float*)d_in[17];
    const float* rope_sin = (const float*)d_in[18];

    float* ws     = (float*)d_ws;
    float* qk     = ws;                       // 33554432 floats (128 MB)
    float* s_sp_q = qk + 33554432;            // 32768
    float* s_sp_k = s_sp_q + 32768;           // 32768
    float* sch_q  = s_sp_k + 32768;           // 4096
    float* sch_k  = sch_q + 4096;             // 4096
    float* pool_q = sch_k + 4096;             // 4096  <- zeroed region starts here
    float* pool_k = pool_q + 4096;            // 4096
    float* kmean  = pool_k + 4096;            // 4096
    float* kv     = kmean + 4096;             // 131072
    _Float16* x_hi = (_Float16*)(kv + 131072);     // 32 MB
    _Float16* x_lo = x_hi + 16777216;              // 32 MB
    _Float16* w_hi = x_lo + 16777216;              // 1 MB
    _Float16* w_lo = w_hi + 524288;                // 1 MB

    hipMemsetAsync(pool_q, 0, (size_t)(3 * 4096 + 131072) * sizeof(float), stream);

    k_split<<<16384, 256, 0, stream>>>((const float4*)x, (half4*)x_hi, (half4*)x_lo, 4194304);
    k_split<<<512, 256, 0, stream>>>((const float4*)qk_w, (half4*)w_hi, (half4*)w_lo, 131072);
    k_gemm_mfma<<<dim3(256, 8), 256, 0, stream>>>(x_hi, x_lo, w_hi, w_lo, qk_b, qk);

    k_spatial<<<dim3(2048, 2), 512, 0, stream>>>(qk,
        qsp_dw_w, qsp_dw_b, qsp_bn_g, qsp_bn_b, qsp_pw_w,
        ksp_dw_w, ksp_dw_b, ksp_bn_g, ksp_bn_b, ksp_pw_w,
        s_sp_q, s_sp_k, pool_q, pool_k);
    k_chsig<<<2048, 256, 0, stream>>>(pool_q, pool_k, qch_w, kch_w, sch_q, sch_k);
    k_kv<<<dim3(128, 8), 256, 0, stream>>>(qk, x, s_sp_k, sch_k, rope_cos, rope_sin,
                                           kv, kmean);
    k_final<<<1024, 512, 0, stream>>>(qk, x, kv, kmean, s_sp_q, sch_q,
                                      rope_cos, rope_sin, lepe_w, lepe_b, (float*)d_out);
}

// Round 11
// 441.178 us; speedup vs baseline: 1.2324x; 1.0596x over previous
//
#include <hip/hip_runtime.h>
#include <cmath>

namespace {

constexpr int CH    = 512;
constexpr int NPIX  = 4096;   // 64*64

typedef _Float16 half8 __attribute__((ext_vector_type(8)));
typedef _Float16 half4 __attribute__((ext_vector_type(4)));
typedef float    f32x4 __attribute__((ext_vector_type(4)));

__device__ __forceinline__ float sigmoidf_(float v) { return 1.0f / (1.0f + expf(-v)); }

// ======================= K0: fp32 -> (hi, lo*1024) f16 split ==============
__global__ __launch_bounds__(256) void k_split(
    const float4* __restrict__ in, half4* __restrict__ hi,
    half4* __restrict__ lo, int n4)
{
    int i = blockIdx.x * 256 + threadIdx.x;
    if (i >= n4) return;
    float4 v = in[i];
    half4 h, l;
    h[0] = (_Float16)v.x; l[0] = (_Float16)((v.x - (float)h[0]) * 1024.0f);
    h[1] = (_Float16)v.y; l[1] = (_Float16)((v.y - (float)h[1]) * 1024.0f);
    h[2] = (_Float16)v.z; l[2] = (_Float16)((v.z - (float)h[2]) * 1024.0f);
    h[3] = (_Float16)v.w; l[3] = (_Float16)((v.w - (float)h[3]) * 1024.0f);
    hi[i] = h; lo[i] = l;
}

// ======================= K1: qk = x @ qk_w^T + qk_b (split-f16 MFMA) ======
// XCD-aware bijective block swizzle: 8 consecutive same-XCD blocks share one
// A-panel (bm), cycling bn 0..7 -> A fetched once per XCD group instead of 8x.
__global__ __launch_bounds__(256, 2) void k_gemm_mfma(
    const _Float16* __restrict__ Ahi, const _Float16* __restrict__ Alo,
    const _Float16* __restrict__ Bhi, const _Float16* __restrict__ Blo,
    const float* __restrict__ bias, float* __restrict__ out)
{
    __shared__ _Float16 lds[4 * 128 * 32];   // Ahi | Alo | Bhi | Blo tiles
    const int t    = threadIdx.x;
    const int wave = t >> 6;
    const int lane = t & 63;

    const int lin = blockIdx.y * 256 + blockIdx.x;    // 0..2047
    const int swz = (lin & 7) * 256 + (lin >> 3);     // bijective (2048%8==0)
    const int bm  = swz >> 3;                         // 0..255
    const int bn  = swz & 7;                          // 0..7

    const _Float16* src;
    switch (wave) {
        case 0: src = Ahi + (size_t)bm * 128 * 512; break;
        case 1: src = Alo + (size_t)bm * 128 * 512; break;
        case 2: src = Bhi + (size_t)bn * 128 * 512; break;
        default: src = Blo + (size_t)bn * 128 * 512; break;
    }
    const _Float16* srcLane = src + (size_t)(lane >> 2) * 512 + (lane & 3) * 8;
    _Float16* ldsW = lds + wave * 4096;

    const int wm = wave >> 1, wn = wave & 1;
    const int mrow = lane & 15;
    const int kq   = (lane >> 4) * 8;
    const _Float16* aH = lds         + (wm * 64 + mrow) * 32 + kq;
    const _Float16* aL = lds + 4096  + (wm * 64 + mrow) * 32 + kq;
    const _Float16* bH = lds + 8192  + (wn * 64 + mrow) * 32 + kq;
    const _Float16* bL = lds + 12288 + (wn * 64 + mrow) * 32 + kq;

    f32x4 acc0[4][4], acc1[4][4];
    #pragma unroll
    for (int i = 0; i < 4; i++)
        #pragma unroll
        for (int j = 0; j < 4; j++) { acc0[i][j] = (f32x4)0.0f; acc1[i][j] = (f32x4)0.0f; }

    for (int k0 = 0; k0 < 16; k0++) {
        const _Float16* g = srcLane + k0 * 32;
        #pragma unroll
        for (int r = 0; r < 8; r++) {
            __builtin_amdgcn_global_load_lds(
                (const __attribute__((address_space(1))) void*)(g + (size_t)r * 16 * 512),
                (__attribute__((address_space(3))) void*)(ldsW + r * 512),
                16, 0, 0);
        }
        __syncthreads();

        half8 ah[4], al[4], bh[4], bl[4];
        #pragma unroll
        for (int i = 0; i < 4; i++) {
            ah[i] = *(const half8*)(aH + i * 16 * 32);
            al[i] = *(const half8*)(aL + i * 16 * 32);
            bh[i] = *(const half8*)(bH + i * 16 * 32);
            bl[i] = *(const half8*)(bL + i * 16 * 32);
        }
        #pragma unroll
        for (int i = 0; i < 4; i++)
            #pragma unroll
            for (int j = 0; j < 4; j++) {
                acc0[i][j] = __builtin_amdgcn_mfma_f32_16x16x32_f16(ah[i], bh[j], acc0[i][j], 0, 0, 0);
                acc1[i][j] = __builtin_amdgcn_mfma_f32_16x16x32_f16(ah[i], bl[j], acc1[i][j], 0, 0, 0);
                acc1[i][j] = __builtin_amdgcn_mfma_f32_16x16x32_f16(al[i], bh[j], acc1[i][j], 0, 0, 0);
            }
        __syncthreads();
    }

    const int ccol = lane & 15;
    const int crow = (lane >> 4) * 4;
    #pragma unroll
    for (int j = 0; j < 4; j++) {
        int col = bn * 128 + wn * 64 + j * 16 + ccol;
        float bv = bias[col];
        #pragma unroll
        for (int i = 0; i < 4; i++) {
            size_t row0 = (size_t)bm * 128 + wm * 64 + i * 16 + crow;
            #pragma unroll
            for (int r = 0; r < 4; r++) {
                float v = acc0[i][j][r] + acc1[i][j][r] * (1.0f / 1024.0f) + bv;
                out[(row0 + r) * 1024 + col] = v;
            }
        }
    }
}

// ======================= K2: spatial gate — sliding window, w-quartered ====
// XCD swizzle: same-XCD blocks are neighboring (h,w) tiles -> qk 3-row
// sliding windows hit in the XCD's L2.
__global__ __launch_bounds__(512) void k_spatial(
    const float* __restrict__ qk,
    const float* __restrict__ dw_w_q, const float* __restrict__ dw_b_q,
    const float* __restrict__ bn_g_q, const float* __restrict__ bn_b_q,
    const float* __restrict__ pw_q,
    const float* __restrict__ dw_w_k, const float* __restrict__ dw_b_k,
    const float* __restrict__ bn_g_k, const float* __restrict__ bn_b_k,
    const float* __restrict__ pw_k,
    float* __restrict__ s_sp_q, float* __restrict__ s_sp_k,
    float* __restrict__ pool_q, float* __restrict__ pool_k)
{
    const int which = blockIdx.y;
    const int lin = blockIdx.x;                    // 0..2047
    const int bx  = (lin & 7) * 256 + (lin >> 3);  // bijective XCD swizzle
    const int b  = bx >> 8;
    const int h  = (bx >> 2) & 63;
    const int w0 = (bx & 3) * 16;
    const int c  = threadIdx.x;
    const float* dw_w = which ? dw_w_k : dw_w_q;
    const float* dw_b = which ? dw_b_k : dw_b_q;
    const float* bn_g = which ? bn_g_k : bn_g_q;
    const float* bn_b = which ? bn_b_k : bn_b_q;
    const float* pw   = which ? pw_k   : pw_q;
    float*       s_sp = which ? s_sp_k : s_sp_q;
    float*       pool = which ? pool_k : pool_q;

    float w9[9];
    #pragma unroll
    for (int j = 0; j < 9; j++) w9[j] = dw_w[c * 9 + j];
    const float bconv = dw_b[c];
    const float bns   = bn_g[c] * (1.0f / sqrtf(1.00001f));
    const float bnb   = bn_b[c];
    const float pwc   = pw[c];

    __shared__ float part[512][17];       // stride-17: conflict-free both passes
    __shared__ float s_row[16];
    const float* inb  = qk + (size_t)b * NPIX * 1024 + (which ? 512 : 0);
    const float* row0 = inb + (size_t)(h * 64) * 1024 + c;
    const float* rowm = row0 - (ptrdiff_t)64 * 1024;   // h-1 (deref-guarded)
    const float* rowp = row0 + (ptrdiff_t)64 * 1024;   // h+1
    const bool hm_ok = (h > 0), hp_ok = (h < 63);

    float x0m, x00, x0p, x1m, x10, x1p, x2m, x20, x2p;
    float cent[16];

    auto LD3 = [&](int wg, float& vm, float& v0, float& vp) {
        bool wok = (wg >= 0) && (wg < 64);
        ptrdiff_t o = (ptrdiff_t)wg * 1024;
        vm = (wok && hm_ok) ? rowm[o] : 0.0f;
        v0 =  wok           ? row0[o] : 0.0f;
        vp = (wok && hp_ok) ? rowp[o] : 0.0f;
    };

    LD3(w0 - 1, x0m, x1m, x2m);
    LD3(w0,     x00, x10, x20);

    #pragma unroll
    for (int i = 0; i < 16; i++) {
        LD3(w0 + i + 1, x0p, x1p, x2p);
        float y = bconv;
        y = fmaf(x0m, w9[0], y); y = fmaf(x00, w9[1], y); y = fmaf(x0p, w9[2], y);
        y = fmaf(x1m, w9[3], y); y = fmaf(x10, w9[4], y); y = fmaf(x1p, w9[5], y);
        y = fmaf(x2m, w9[6], y); y = fmaf(x2p, w9[8], fmaf(x20, w9[7], y));
        y = fmaxf(fmaf(y, bns, bnb), 0.0f);
        cent[i] = x10;
        part[c][i] = y * pwc;
        x0m = x00; x00 = x0p;
        x1m = x10; x10 = x1p;
        x2m = x20; x20 = x2p;
    }
    __syncthreads();
    {
        const int p = c >> 5;             // pixel 0..15
        const int j = c & 31;             // reducer lane within 32-group
        float s = 0.0f;
        #pragma unroll
        for (int m = 0; m < 16; m++) s += part[j + 32 * m][p];
        #pragma unroll
        for (int off = 16; off > 0; off >>= 1) s += __shfl_xor(s, off, 32);
        if (j == 0) {
            float sg = sigmoidf_(s);
            s_row[p] = sg;
            s_sp[(size_t)b * NPIX + h * 64 + w0 + p] = sg;
        }
    }
    __syncthreads();
    float pacc = 0.0f;
    #pragma unroll
    for (int i = 0; i < 16; i++) pacc = fmaf(cent[i], s_row[i], pacc);
    atomicAdd(&pool[(size_t)b * CH + c], pacc);
}

// ======================= K3: channel sigmoid ===============================
__global__ __launch_bounds__(256) void k_chsig(
    const float* __restrict__ pool_q, const float* __restrict__ pool_k,
    const float* __restrict__ qch_w,  const float* __restrict__ kch_w,
    float* __restrict__ sch_q, float* __restrict__ sch_k)
{
    int id    = blockIdx.x;           // 0..2047
    int which = id >> 10;
    int rem   = id & 1023;
    int b     = rem >> 7;             // 0..7
    int og    = rem & 127;            // 0..127
    int wid   = threadIdx.x >> 6, lane = threadIdx.x & 63;
    int o     = og * 4 + wid;
    const float* pool = which ? pool_k : pool_q;
    const float* Wt   = which ? kch_w  : qch_w;
    float s = 0.0f;
    for (int cc = lane; cc < CH; cc += 64) s = fmaf(pool[b * CH + cc], Wt[o * CH + cc], s);
    #pragma unroll
    for (int off = 32; off > 0; off >>= 1) s += __shfl_down(s, off, 64);
    if (lane == 0)
        (which ? sch_k : sch_q)[b * CH + o] = sigmoidf_(s * (1.0f / 4096.0f));
}

// ======================= K4: kv accumulate, rope(k) fused in-register ======
__global__ __launch_bounds__(256) void k_kv(
    const float* __restrict__ qk, const float* __restrict__ x,
    const float* __restrict__ s_sp_k, const float* __restrict__ sch_k,
    const float* __restrict__ cosT,   const float* __restrict__ sinT,
    float* __restrict__ kv, float* __restrict__ kmean)
{
    const int bh = blockIdx.x;      // 0..127
    const int b  = bh >> 4, hh = bh & 15;
    const int n0 = blockIdx.y * 512;
    __shared__ float kt[32][33];
    __shared__ float vt[32][33];
    const int t  = threadIdx.x;
    const int e  = t & 31, d0 = (t >> 5) * 4;
    const int nn  = t >> 3;
    const int cc4 = (t & 7) * 4;
    const int cg  = hh * 32 + cc4;          // global channel of lane's quad
    const int kidx = cg >> 1;               // rope pair index (even)

    const float sch0 = sch_k[b * CH + cg + 0];
    const float sch1 = sch_k[b * CH + cg + 1];
    const float sch2 = sch_k[b * CH + cg + 2];
    const float sch3 = sch_k[b * CH + cg + 3];

    float km0 = 0.f, km1 = 0.f, km2 = 0.f, km3 = 0.f;
    float acc[4] = {0.f, 0.f, 0.f, 0.f};
    for (int s = 0; s < 512; s += 32) {
        const int n = n0 + s + nn;
        size_t rowbase = (size_t)(b * NPIX + n);
        float4 kvv = *(const float4*)(qk + rowbase * 1024 + 512 + cg);
        const float ssp = s_sp_k[(size_t)b * NPIX + n];
        float g0 = kvv.x * ssp * sch0;
        float g1 = kvv.y * ssp * sch1;
        float g2 = kvv.z * ssp * sch2;
        float g3 = kvv.w * ssp * sch3;
        float e0 = g0 > 0.0f ? g0 + 1.0f : expf(g0);
        float e1 = g1 > 0.0f ? g1 + 1.0f : expf(g1);
        float e2 = g2 > 0.0f ? g2 + 1.0f : expf(g2);
        float e3 = g3 > 0.0f ? g3 + 1.0f : expf(g3);
        const float cs0 = cosT[(size_t)n * 256 + kidx];
        const float sn0 = sinT[(size_t)n * 256 + kidx];
        const float cs1 = cosT[(size_t)n * 256 + kidx + 1];
        const float sn1 = sinT[(size_t)n * 256 + kidx + 1];
        float r0 = fmaf(cs0, e0, -(sn0 * e1));
        float r1 = fmaf(sn0, e0,   cs0 * e1);
        float r2 = fmaf(cs1, e2, -(sn1 * e3));
        float r3 = fmaf(sn1, e2,   cs1 * e3);
        kt[nn][cc4] = r0; kt[nn][cc4+1] = r1; kt[nn][cc4+2] = r2; kt[nn][cc4+3] = r3;
        km0 += r0; km1 += r1; km2 += r2; km3 += r3;
        float4 vv  = *(const float4*)(x + rowbase * 512 + cg);
        vt[nn][cc4] = vv.x; vt[nn][cc4+1] = vv.y; vt[nn][cc4+2] = vv.z; vt[nn][cc4+3] = vv.w;
        __syncthreads();
        #pragma unroll
        for (int q = 0; q < 32; q++) {
            float vq = vt[q][e];
            acc[0] = fmaf(kt[q][d0    ], vq, acc[0]);
            acc[1] = fmaf(kt[q][d0 + 1], vq, acc[1]);
            acc[2] = fmaf(kt[q][d0 + 2], vq, acc[2]);
            acc[3] = fmaf(kt[q][d0 + 3], vq, acc[3]);
        }
        __syncthreads();
    }
    #pragma unroll
    for (int i = 0; i < 4; i++)
        atomicAdd(&kv[((size_t)bh * 32 + d0 + i) * 32 + e], acc[i]);
    atomicAdd(&kmean[(size_t)b * CH + cg + 0], km0);
    atomicAdd(&kmean[(size_t)b * CH + cg + 1], km1);
    atomicAdd(&kmean[(size_t)b * CH + cg + 2], km2);
    atomicAdd(&kmean[(size_t)b * CH + cg + 3], km3);
}

// ======================= K5: out = (q_r @ kv)*z + lepe — rope(q) fused =====
// XCD swizzle: same-XCD blocks share x halo rows + per-b kv/kmean in L2.
__global__ __launch_bounds__(512) void k_final(
    const float* __restrict__ qk, const float* __restrict__ x,
    const float* __restrict__ kvbuf, const float* __restrict__ kmean,
    const float* __restrict__ s_sp_q, const float* __restrict__ sch_q,
    const float* __restrict__ cosT,   const float* __restrict__ sinT,
    const float* __restrict__ lepe_w, const float* __restrict__ lepe_b,
    float* __restrict__ out)
{
    const int lin = blockIdx.x;                    // 0..1023
    const int bx  = (lin & 7) * 128 + (lin >> 3);  // bijective XCD swizzle
    const int b  = bx >> 7;
    const int h  = (bx >> 1) & 63;
    const int w0 = (bx & 1) * 32;
    const int c  = threadIdx.x;
    const int e  = c & 31;
    const int head = c >> 5;
    const int kidx = c >> 1;
    const int odd  = c & 1;

    __shared__ float qv_lds[16][40];      // 160B rows: 16B aligned, bank-spread

    float kvreg[32], kmreg[32];
    #pragma unroll
    for (int d = 0; d < 32; d++)
        kvreg[d] = kvbuf[((size_t)b * 16 + head) * 1024 + d * 32 + e] * (1.0f / 4096.0f);
    #pragma unroll
    for (int d = 0; d < 32; d++)
        kmreg[d] = kmean[(size_t)b * CH + head * 32 + d] * (1.0f / 4096.0f);
    const float schc = sch_q[(size_t)b * CH + c];
    float w9[9];
    #pragma unroll
    for (int j = 0; j < 9; j++) w9[j] = lepe_w[c * 9 + j];
    const float lb = lepe_b[c];

    const float* xr0 = x + ((size_t)b * NPIX + h * 64) * 512 + c;
    const float* xrm = xr0 - (ptrdiff_t)64 * 512;
    const float* xrp = xr0 + (ptrdiff_t)64 * 512;
    const bool hm_ok = (h > 0), hp_ok = (h < 63);
    const float* qkb = qk + ((size_t)b * NPIX + h * 64) * 1024 + c;
    const float* ssb = s_sp_q + (size_t)b * NPIX + h * 64;
    const float* csb = cosT + (size_t)(h * 64) * 256 + kidx;
    const float* snb = sinT + (size_t)(h * 64) * 256 + kidx;
    float* outb = out + ((size_t)b * NPIX + h * 64) * 512 + c;

    float x0m, x00, x0p, x1m, x10, x1p, x2m, x20, x2p;
    auto LD3 = [&](int wg, float& vm, float& v0, float& vp) {
        bool wok = (wg >= 0) && (wg < 64);
        ptrdiff_t o = (ptrdiff_t)wg * 512;
        vm = (wok && hm_ok) ? xrm[o] : 0.0f;
        v0 =  wok           ? xr0[o] : 0.0f;
        vp = (wok && hp_ok) ? xrp[o] : 0.0f;
    };
    LD3(w0 - 1, x0m, x1m, x2m);
    LD3(w0,     x00, x10, x20);

    // depth-1 prefetch of per-pixel scalars
    float qraw = qkb[(size_t)w0 * 1024];
    float ssp  = ssb[w0];
    float cs   = csb[(size_t)w0 * 256];
    float sn   = snb[(size_t)w0 * 256];

    for (int i = 0; i < 32; i++) {
        const int wg = w0 + i;
        float x0p_, x1p_, x2p_;
        LD3(wg + 1, x0p_, x1p_, x2p_);
        x0p = x0p_; x1p = x1p_; x2p = x2p_;

        float qraw_n = 0.0f, ssp_n = 0.0f, cs_n = 0.0f, sn_n = 0.0f;
        if (i < 31) {
            qraw_n = qkb[(size_t)(wg + 1) * 1024];
            ssp_n  = ssb[wg + 1];
            cs_n   = csb[(size_t)(wg + 1) * 256];
            sn_n   = snb[(size_t)(wg + 1) * 256];
        }

        // --- fused gate + elu + rope for q ---
        float g    = qraw * ssp * schc;
        float eV   = g > 0.0f ? g + 1.0f : expf(g);
        float part = __shfl_xor(eV, 1, 64);
        float qv   = odd ? fmaf(sn, part, cs * eV) : fmaf(cs, eV, -(sn * part));

        qv_lds[head][e] = qv;

        float num0 = 0.0f, num1 = 0.0f, num2 = 0.0f, num3 = 0.0f;
        float den0 = 0.0f, den1 = 0.0f, den2 = 0.0f, den3 = 0.0f;
        #pragma unroll
        for (int dq = 0; dq < 8; dq++) {
            float4 q4 = *(const float4*)&qv_lds[head][dq * 4];
            num0 = fmaf(q4.x, kvreg[dq * 4 + 0], num0);
            num1 = fmaf(q4.y, kvreg[dq * 4 + 1], num1);
            num2 = fmaf(q4.z, kvreg[dq * 4 + 2], num2);
            num3 = fmaf(q4.w, kvreg[dq * 4 + 3], num3);
            den0 = fmaf(q4.x, kmreg[dq * 4 + 0], den0);
            den1 = fmaf(q4.y, kmreg[dq * 4 + 1], den1);
            den2 = fmaf(q4.z, kmreg[dq * 4 + 2], den2);
            den3 = fmaf(q4.w, kmreg[dq * 4 + 3], den3);
        }
        float num = (num0 + num1) + (num2 + num3);
        float den = (den0 + den1) + (den2 + den3);
        float z = 1.0f / (den + 1e-6f);

        float lp = lb;
        lp = fmaf(x0m, w9[0], lp); lp = fmaf(x00, w9[1], lp); lp = fmaf(x0p, w9[2], lp);
        lp = fmaf(x1m, w9[3], lp); lp = fmaf(x10, w9[4], lp); lp = fmaf(x1p, w9[5], lp);
        lp = fmaf(x2m, w9[6], lp); lp = fmaf(x20, w9[7], lp);

        outb[(size_t)wg * 512] = fmaf(num, z, fmaf(x2p, w9[8], lp));

        qraw = qraw_n; ssp = ssp_n; cs = cs_n; sn = sn_n;
        x0m = x00; x00 = x0p;
        x1m = x10; x10 = x1p;
        x2m = x20; x20 = x2p;
    }
}

} // namespace

extern "C" void kernel_launch(void* const* d_in, const int* in_sizes, int n_in,
                              void* d_out, int out_size, void* d_ws, size_t ws_size,
                              hipStream_t stream)
{
    (void)in_sizes; (void)n_in; (void)out_size; (void)ws_size;
    const float* x        = (const float*)d_in[0];
    const float* qk_w     = (const float*)d_in[1];
    const float* qk_b     = (const float*)d_in[2];
    const float* qsp_dw_w = (const float*)d_in[3];
    const float* qsp_dw_b = (const float*)d_in[4];
    const float* qsp_bn_g = (const float*)d_in[5];
    const float* qsp_bn_b = (const float*)d_in[6];
    const float* qsp_pw_w = (const float*)d_in[7];
    const float* qch_w    = (const float*)d_in[8];
    const float* ksp_dw_w = (const float*)d_in[9];
    const float* ksp_dw_b = (const float*)d_in[10];
    const float* ksp_bn_g = (const float*)d_in[11];
    const float* ksp_bn_b = (const float*)d_in[12];
    const float* ksp_pw_w = (const float*)d_in[13];
    const float* kch_w    = (const float*)d_in[14];
    const float* lepe_w   = (const float*)d_in[15];
    const float* lepe_b   = (const float*)d_in[16];
    const float* rope_cos = (const float*)d_in[17];
    const float* rope_sin = (const float*)d_in[18];

    float* ws     = (float*)d_ws;
    float* qk     = ws;                       // 33554432 floats (128 MB)
    float* s_sp_q = qk + 33554432;            // 32768
    float* s_sp_k = s_sp_q + 32768;           // 32768
    float* sch_q  = s_sp_k + 32768;           // 4096
    float* sch_k  = sch_q + 4096;             // 4096
    float* pool_q = sch_k + 4096;             // 4096  <- zeroed region starts here
    float* pool_k = pool_q + 4096;            // 4096
    float* kmean  = pool_k + 4096;            // 4096
    float* kv     = kmean + 4096;             // 131072
    _Float16* x_hi = (_Float16*)(kv + 131072);     // 32 MB
    _Float16* x_lo = x_hi + 16777216;              // 32 MB
    _Float16* w_hi = x_lo + 16777216;              // 1 MB
    _Float16* w_lo = w_hi + 524288;                // 1 MB

    hipMemsetAsync(pool_q, 0, (size_t)(3 * 4096 + 131072) * sizeof(float), stream);

    k_split<<<16384, 256, 0, stream>>>((const float4*)x, (half4*)x_hi, (half4*)x_lo, 4194304);
    k_split<<<512, 256, 0, stream>>>((const float4*)qk_w, (half4*)w_hi, (half4*)w_lo, 131072);
    k_gemm_mfma<<<dim3(256, 8), 256, 0, stream>>>(x_hi, x_lo, w_hi, w_lo, qk_b, qk);

    k_spatial<<<dim3(2048, 2), 512, 0, stream>>>(qk,
        qsp_dw_w, qsp_dw_b, qsp_bn_g, qsp_bn_b, qsp_pw_w,
        ksp_dw_w, ksp_dw_b, ksp_bn_g, ksp_bn_b, ksp_pw_w,
        s_sp_q, s_sp_k, pool_q, pool_k);
    k_chsig<<<2048, 256, 0, stream>>>(pool_q, pool_k, qch_w, kch_w, sch_q, sch_k);
    k_kv<<<dim3(128, 8), 256, 0, stream>>>(qk, x, s_sp_k, sch_k, rope_cos, rope_sin,
                                           kv, kmean);
    k_final<<<1024, 512, 0, stream>>>(qk, x, kv, kmean, s_sp_q, sch_q,
                                      rope_cos, rope_sin, lepe_w, lepe_b, (float*)d_out);
}

// Round 12
// 436.278 us; speedup vs baseline: 1.2463x; 1.0112x over previous
//
#include <hip/hip_runtime.h>
#include <cmath>

namespace {

constexpr int CH    = 512;
constexpr int NPIX  = 4096;   // 64*64

typedef _Float16 half8 __attribute__((ext_vector_type(8)));
typedef _Float16 half4 __attribute__((ext_vector_type(4)));
typedef float    f32x4 __attribute__((ext_vector_type(4)));

__device__ __forceinline__ float sigmoidf_(float v) { return 1.0f / (1.0f + expf(-v)); }

// ======================= K0: fused prep — zero accumulators + both splits ==
// blocks [0,140): zero pool_q..kv (143360 floats = 140*256*4 exactly)
// blocks [140,652): split qk_w (131072 float4)
// blocks [652,17036): split x (4194304 float4)
// All jobs independent; consumers are in later dispatches.
__global__ __launch_bounds__(256) void k_prep(
    const float4* __restrict__ x, const float4* __restrict__ w,
    half4* __restrict__ x_hi, half4* __restrict__ x_lo,
    half4* __restrict__ w_hi, half4* __restrict__ w_lo,
    float4* __restrict__ zero_base)
{
    const int blk = blockIdx.x;
    const int tid = threadIdx.x;
    if (blk < 140) {
        zero_base[blk * 256 + tid] = float4{0.f, 0.f, 0.f, 0.f};
        return;
    }
    const float4* in;
    half4* hi;
    half4* lo;
    int i;
    if (blk < 652) {
        i = (blk - 140) * 256 + tid;           // 0..131071
        in = w; hi = w_hi; lo = w_lo;
    } else {
        i = (blk - 652) * 256 + tid;           // 0..4194303
        in = x; hi = x_hi; lo = x_lo;
    }
    float4 v = in[i];
    half4 h, l;
    h[0] = (_Float16)v.x; l[0] = (_Float16)((v.x - (float)h[0]) * 1024.0f);
    h[1] = (_Float16)v.y; l[1] = (_Float16)((v.y - (float)h[1]) * 1024.0f);
    h[2] = (_Float16)v.z; l[2] = (_Float16)((v.z - (float)h[2]) * 1024.0f);
    h[3] = (_Float16)v.w; l[3] = (_Float16)((v.w - (float)h[3]) * 1024.0f);
    hi[i] = h; lo[i] = l;
}

// ======================= K1: qk = x @ qk_w^T + qk_b (split-f16 MFMA) ======
// XCD-aware bijective block swizzle: 8 consecutive same-XCD blocks share one
// A-panel (bm), cycling bn 0..7 -> A fetched once per XCD group instead of 8x.
__global__ __launch_bounds__(256, 2) void k_gemm_mfma(
    const _Float16* __restrict__ Ahi, const _Float16* __restrict__ Alo,
    const _Float16* __restrict__ Bhi, const _Float16* __restrict__ Blo,
    const float* __restrict__ bias, float* __restrict__ out)
{
    __shared__ _Float16 lds[4 * 128 * 32];   // Ahi | Alo | Bhi | Blo tiles
    const int t    = threadIdx.x;
    const int wave = t >> 6;
    const int lane = t & 63;

    const int lin = blockIdx.y * 256 + blockIdx.x;    // 0..2047
    const int swz = (lin & 7) * 256 + (lin >> 3);     // bijective (2048%8==0)
    const int bm  = swz >> 3;                         // 0..255
    const int bn  = swz & 7;                          // 0..7

    const _Float16* src;
    switch (wave) {
        case 0: src = Ahi + (size_t)bm * 128 * 512; break;
        case 1: src = Alo + (size_t)bm * 128 * 512; break;
        case 2: src = Bhi + (size_t)bn * 128 * 512; break;
        default: src = Blo + (size_t)bn * 128 * 512; break;
    }
    const _Float16* srcLane = src + (size_t)(lane >> 2) * 512 + (lane & 3) * 8;
    _Float16* ldsW = lds + wave * 4096;

    const int wm = wave >> 1, wn = wave & 1;
    const int mrow = lane & 15;
    const int kq   = (lane >> 4) * 8;
    const _Float16* aH = lds         + (wm * 64 + mrow) * 32 + kq;
    const _Float16* aL = lds + 4096  + (wm * 64 + mrow) * 32 + kq;
    const _Float16* bH = lds + 8192  + (wn * 64 + mrow) * 32 + kq;
    const _Float16* bL = lds + 12288 + (wn * 64 + mrow) * 32 + kq;

    f32x4 acc0[4][4], acc1[4][4];
    #pragma unroll
    for (int i = 0; i < 4; i++)
        #pragma unroll
        for (int j = 0; j < 4; j++) { acc0[i][j] = (f32x4)0.0f; acc1[i][j] = (f32x4)0.0f; }

    for (int k0 = 0; k0 < 16; k0++) {
        const _Float16* g = srcLane + k0 * 32;
        #pragma unroll
        for (int r = 0; r < 8; r++) {
            __builtin_amdgcn_global_load_lds(
                (const __attribute__((address_space(1))) void*)(g + (size_t)r * 16 * 512),
                (__attribute__((address_space(3))) void*)(ldsW + r * 512),
                16, 0, 0);
        }
        __syncthreads();

        half8 ah[4], al[4], bh[4], bl[4];
        #pragma unroll
        for (int i = 0; i < 4; i++) {
            ah[i] = *(const half8*)(aH + i * 16 * 32);
            al[i] = *(const half8*)(aL + i * 16 * 32);
            bh[i] = *(const half8*)(bH + i * 16 * 32);
            bl[i] = *(const half8*)(bL + i * 16 * 32);
        }
        #pragma unroll
        for (int i = 0; i < 4; i++)
            #pragma unroll
            for (int j = 0; j < 4; j++) {
                acc0[i][j] = __builtin_amdgcn_mfma_f32_16x16x32_f16(ah[i], bh[j], acc0[i][j], 0, 0, 0);
                acc1[i][j] = __builtin_amdgcn_mfma_f32_16x16x32_f16(ah[i], bl[j], acc1[i][j], 0, 0, 0);
                acc1[i][j] = __builtin_amdgcn_mfma_f32_16x16x32_f16(al[i], bh[j], acc1[i][j], 0, 0, 0);
            }
        __syncthreads();
    }

    const int ccol = lane & 15;
    const int crow = (lane >> 4) * 4;
    #pragma unroll
    for (int j = 0; j < 4; j++) {
        int col = bn * 128 + wn * 64 + j * 16 + ccol;
        float bv = bias[col];
        #pragma unroll
        for (int i = 0; i < 4; i++) {
            size_t row0 = (size_t)bm * 128 + wm * 64 + i * 16 + crow;
            #pragma unroll
            for (int r = 0; r < 4; r++) {
                float v = acc0[i][j][r] + acc1[i][j][r] * (1.0f / 1024.0f) + bv;
                out[(row0 + r) * 1024 + col] = v;
            }
        }
    }
}

// ======================= K2: spatial gate — sliding window, w-quartered ====
// XCD swizzle: same-XCD blocks are neighboring (h,w) tiles -> qk 3-row
// sliding windows hit in the XCD's L2.
__global__ __launch_bounds__(512) void k_spatial(
    const float* __restrict__ qk,
    const float* __restrict__ dw_w_q, const float* __restrict__ dw_b_q,
    const float* __restrict__ bn_g_q, const float* __restrict__ bn_b_q,
    const float* __restrict__ pw_q,
    const float* __restrict__ dw_w_k, const float* __restrict__ dw_b_k,
    const float* __restrict__ bn_g_k, const float* __restrict__ bn_b_k,
    const float* __restrict__ pw_k,
    float* __restrict__ s_sp_q, float* __restrict__ s_sp_k,
    float* __restrict__ pool_q, float* __restrict__ pool_k)
{
    const int which = blockIdx.y;
    const int lin = blockIdx.x;                    // 0..2047
    const int bx  = (lin & 7) * 256 + (lin >> 3);  // bijective XCD swizzle
    const int b  = bx >> 8;
    const int h  = (bx >> 2) & 63;
    const int w0 = (bx & 3) * 16;
    const int c  = threadIdx.x;
    const float* dw_w = which ? dw_w_k : dw_w_q;
    const float* dw_b = which ? dw_b_k : dw_b_q;
    const float* bn_g = which ? bn_g_k : bn_g_q;
    const float* bn_b = which ? bn_b_k : bn_b_q;
    const float* pw   = which ? pw_k   : pw_q;
    float*       s_sp = which ? s_sp_k : s_sp_q;
    float*       pool = which ? pool_k : pool_q;

    float w9[9];
    #pragma unroll
    for (int j = 0; j < 9; j++) w9[j] = dw_w[c * 9 + j];
    const float bconv = dw_b[c];
    const float bns   = bn_g[c] * (1.0f / sqrtf(1.00001f));
    const float bnb   = bn_b[c];
    const float pwc   = pw[c];

    __shared__ float part[512][17];       // stride-17: conflict-free both passes
    __shared__ float s_row[16];
    const float* inb  = qk + (size_t)b * NPIX * 1024 + (which ? 512 : 0);
    const float* row0 = inb + (size_t)(h * 64) * 1024 + c;
    const float* rowm = row0 - (ptrdiff_t)64 * 1024;   // h-1 (deref-guarded)
    const float* rowp = row0 + (ptrdiff_t)64 * 1024;   // h+1
    const bool hm_ok = (h > 0), hp_ok = (h < 63);

    float x0m, x00, x0p, x1m, x10, x1p, x2m, x20, x2p;
    float cent[16];

    auto LD3 = [&](int wg, float& vm, float& v0, float& vp) {
        bool wok = (wg >= 0) && (wg < 64);
        ptrdiff_t o = (ptrdiff_t)wg * 1024;
        vm = (wok && hm_ok) ? rowm[o] : 0.0f;
        v0 =  wok           ? row0[o] : 0.0f;
        vp = (wok && hp_ok) ? rowp[o] : 0.0f;
    };

    LD3(w0 - 1, x0m, x1m, x2m);
    LD3(w0,     x00, x10, x20);

    #pragma unroll
    for (int i = 0; i < 16; i++) {
        LD3(w0 + i + 1, x0p, x1p, x2p);
        float y = bconv;
        y = fmaf(x0m, w9[0], y); y = fmaf(x00, w9[1], y); y = fmaf(x0p, w9[2], y);
        y = fmaf(x1m, w9[3], y); y = fmaf(x10, w9[4], y); y = fmaf(x1p, w9[5], y);
        y = fmaf(x2m, w9[6], y); y = fmaf(x2p, w9[8], fmaf(x20, w9[7], y));
        y = fmaxf(fmaf(y, bns, bnb), 0.0f);
        cent[i] = x10;
        part[c][i] = y * pwc;
        x0m = x00; x00 = x0p;
        x1m = x10; x10 = x1p;
        x2m = x20; x20 = x2p;
    }
    __syncthreads();
    {
        const int p = c >> 5;             // pixel 0..15
        const int j = c & 31;             // reducer lane within 32-group
        float s = 0.0f;
        #pragma unroll
        for (int m = 0; m < 16; m++) s += part[j + 32 * m][p];
        #pragma unroll
        for (int off = 16; off > 0; off >>= 1) s += __shfl_xor(s, off, 32);
        if (j == 0) {
            float sg = sigmoidf_(s);
            s_row[p] = sg;
            s_sp[(size_t)b * NPIX + h * 64 + w0 + p] = sg;
        }
    }
    __syncthreads();
    float pacc = 0.0f;
    #pragma unroll
    for (int i = 0; i < 16; i++) pacc = fmaf(cent[i], s_row[i], pacc);
    atomicAdd(&pool[(size_t)b * CH + c], pacc);
}

// ======================= K3: channel sigmoid ===============================
__global__ __launch_bounds__(256) void k_chsig(
    const float* __restrict__ pool_q, const float* __restrict__ pool_k,
    const float* __restrict__ qch_w,  const float* __restrict__ kch_w,
    float* __restrict__ sch_q, float* __restrict__ sch_k)
{
    int id    = blockIdx.x;           // 0..2047
    int which = id >> 10;
    int rem   = id & 1023;
    int b     = rem >> 7;             // 0..7
    int og    = rem & 127;            // 0..127
    int wid   = threadIdx.x >> 6, lane = threadIdx.x & 63;
    int o     = og * 4 + wid;
    const float* pool = which ? pool_k : pool_q;
    const float* Wt   = which ? kch_w  : qch_w;
    float s = 0.0f;
    for (int cc = lane; cc < CH; cc += 64) s = fmaf(pool[b * CH + cc], Wt[o * CH + cc], s);
    #pragma unroll
    for (int off = 32; off > 0; off >>= 1) s += __shfl_down(s, off, 64);
    if (lane == 0)
        (which ? sch_k : sch_q)[b * CH + o] = sigmoidf_(s * (1.0f / 4096.0f));
}

// ======================= K4: kv accumulate, rope(k) fused in-register ======
__global__ __launch_bounds__(256) void k_kv(
    const float* __restrict__ qk, const float* __restrict__ x,
    const float* __restrict__ s_sp_k, const float* __restrict__ sch_k,
    const float* __restrict__ cosT,   const float* __restrict__ sinT,
    float* __restrict__ kv, float* __restrict__ kmean)
{
    const int bh = blockIdx.x;      // 0..127
    const int b  = bh >> 4, hh = bh & 15;
    const int n0 = blockIdx.y * 512;
    __shared__ float kt[32][33];
    __shared__ float vt[32][33];
    const int t  = threadIdx.x;
    const int e  = t & 31, d0 = (t >> 5) * 4;
    const int nn  = t >> 3;
    const int cc4 = (t & 7) * 4;
    const int cg  = hh * 32 + cc4;          // global channel of lane's quad
    const int kidx = cg >> 1;               // rope pair index (even)

    const float sch0 = sch_k[b * CH + cg + 0];
    const float sch1 = sch_k[b * CH + cg + 1];
    const float sch2 = sch_k[b * CH + cg + 2];
    const float sch3 = sch_k[b * CH + cg + 3];

    float km0 = 0.f, km1 = 0.f, km2 = 0.f, km3 = 0.f;
    float acc[4] = {0.f, 0.f, 0.f, 0.f};
    for (int s = 0; s < 512; s += 32) {
        const int n = n0 + s + nn;
        size_t rowbase = (size_t)(b * NPIX + n);
        float4 kvv = *(const float4*)(qk + rowbase * 1024 + 512 + cg);
        const float ssp = s_sp_k[(size_t)b * NPIX + n];
        float g0 = kvv.x * ssp * sch0;
        float g1 = kvv.y * ssp * sch1;
        float g2 = kvv.z * ssp * sch2;
        float g3 = kvv.w * ssp * sch3;
        float e0 = g0 > 0.0f ? g0 + 1.0f : expf(g0);
        float e1 = g1 > 0.0f ? g1 + 1.0f : expf(g1);
        float e2 = g2 > 0.0f ? g2 + 1.0f : expf(g2);
        float e3 = g3 > 0.0f ? g3 + 1.0f : expf(g3);
        const float cs0 = cosT[(size_t)n * 256 + kidx];
        const float sn0 = sinT[(size_t)n * 256 + kidx];
        const float cs1 = cosT[(size_t)n * 256 + kidx + 1];
        const float sn1 = sinT[(size_t)n * 256 + kidx + 1];
        float r0 = fmaf(cs0, e0, -(sn0 * e1));
        float r1 = fmaf(sn0, e0,   cs0 * e1);
        float r2 = fmaf(cs1, e2, -(sn1 * e3));
        float r3 = fmaf(sn1, e2,   cs1 * e3);
        kt[nn][cc4] = r0; kt[nn][cc4+1] = r1; kt[nn][cc4+2] = r2; kt[nn][cc4+3] = r3;
        km0 += r0; km1 += r1; km2 += r2; km3 += r3;
        float4 vv  = *(const float4*)(x + rowbase * 512 + cg);
        vt[nn][cc4] = vv.x; vt[nn][cc4+1] = vv.y; vt[nn][cc4+2] = vv.z; vt[nn][cc4+3] = vv.w;
        __syncthreads();
        #pragma unroll
        for (int q = 0; q < 32; q++) {
            float vq = vt[q][e];
            acc[0] = fmaf(kt[q][d0    ], vq, acc[0]);
            acc[1] = fmaf(kt[q][d0 + 1], vq, acc[1]);
            acc[2] = fmaf(kt[q][d0 + 2], vq, acc[2]);
            acc[3] = fmaf(kt[q][d0 + 3], vq, acc[3]);
        }
        __syncthreads();
    }
    #pragma unroll
    for (int i = 0; i < 4; i++)
        atomicAdd(&kv[((size_t)bh * 32 + d0 + i) * 32 + e], acc[i]);
    atomicAdd(&kmean[(size_t)b * CH + cg + 0], km0);
    atomicAdd(&kmean[(size_t)b * CH + cg + 1], km1);
    atomicAdd(&kmean[(size_t)b * CH + cg + 2], km2);
    atomicAdd(&kmean[(size_t)b * CH + cg + 3], km3);
}

// ======================= K5: out = (q_r @ kv)*z + lepe — rope(q) fused =====
// XCD swizzle: same-XCD blocks share x halo rows + per-b kv/kmean in L2.
__global__ __launch_bounds__(512) void k_final(
    const float* __restrict__ qk, const float* __restrict__ x,
    const float* __restrict__ kvbuf, const float* __restrict__ kmean,
    const float* __restrict__ s_sp_q, const float* __restrict__ sch_q,
    const float* __restrict__ cosT,   const float* __restrict__ sinT,
    const float* __restrict__ lepe_w, const float* __restrict__ lepe_b,
    float* __restrict__ out)
{
    const int lin = blockIdx.x;                    // 0..1023
    const int bx  = (lin & 7) * 128 + (lin >> 3);  // bijective XCD swizzle
    const int b  = bx >> 7;
    const int h  = (bx >> 1) & 63;
    const int w0 = (bx & 1) * 32;
    const int c  = threadIdx.x;
    const int e  = c & 31;
    const int head = c >> 5;
    const int kidx = c >> 1;
    const int odd  = c & 1;

    __shared__ float qv_lds[16][40];      // 160B rows: 16B aligned, bank-spread

    float kvreg[32], kmreg[32];
    #pragma unroll
    for (int d = 0; d < 32; d++)
        kvreg[d] = kvbuf[((size_t)b * 16 + head) * 1024 + d * 32 + e] * (1.0f / 4096.0f);
    #pragma unroll
    for (int d = 0; d < 32; d++)
        kmreg[d] = kmean[(size_t)b * CH + head * 32 + d] * (1.0f / 4096.0f);
    const float schc = sch_q[(size_t)b * CH + c];
    float w9[9];
    #pragma unroll
    for (int j = 0; j < 9; j++) w9[j] = lepe_w[c * 9 + j];
    const float lb = lepe_b[c];

    const float* xr0 = x + ((size_t)b * NPIX + h * 64) * 512 + c;
    const float* xrm = xr0 - (ptrdiff_t)64 * 512;
    const float* xrp = xr0 + (ptrdiff_t)64 * 512;
    const bool hm_ok = (h > 0), hp_ok = (h < 63);
    const float* qkb = qk + ((size_t)b * NPIX + h * 64) * 1024 + c;
    const float* ssb = s_sp_q + (size_t)b * NPIX + h * 64;
    const float* csb = cosT + (size_t)(h * 64) * 256 + kidx;
    const float* snb = sinT + (size_t)(h * 64) * 256 + kidx;
    float* outb = out + ((size_t)b * NPIX + h * 64) * 512 + c;

    float x0m, x00, x0p, x1m, x10, x1p, x2m, x20, x2p;
    auto LD3 = [&](int wg, float& vm, float& v0, float& vp) {
        bool wok = (wg >= 0) && (wg < 64);
        ptrdiff_t o = (ptrdiff_t)wg * 512;
        vm = (wok && hm_ok) ? xrm[o] : 0.0f;
        v0 =  wok           ? xr0[o] : 0.0f;
        vp = (wok && hp_ok) ? xrp[o] : 0.0f;
    };
    LD3(w0 - 1, x0m, x1m, x2m);
    LD3(w0,     x00, x10, x20);

    // depth-1 prefetch of per-pixel scalars
    float qraw = qkb[(size_t)w0 * 1024];
    float ssp  = ssb[w0];
    float cs   = csb[(size_t)w0 * 256];
    float sn   = snb[(size_t)w0 * 256];

    for (int i = 0; i < 32; i++) {
        const int wg = w0 + i;
        float x0p_, x1p_, x2p_;
        LD3(wg + 1, x0p_, x1p_, x2p_);
        x0p = x0p_; x1p = x1p_; x2p = x2p_;

        float qraw_n = 0.0f, ssp_n = 0.0f, cs_n = 0.0f, sn_n = 0.0f;
        if (i < 31) {
            qraw_n = qkb[(size_t)(wg + 1) * 1024];
            ssp_n  = ssb[wg + 1];
            cs_n   = csb[(size_t)(wg + 1) * 256];
            sn_n   = snb[(size_t)(wg + 1) * 256];
        }

        // --- fused gate + elu + rope for q ---
        float g    = qraw * ssp * schc;
        float eV   = g > 0.0f ? g + 1.0f : expf(g);
        float part = __shfl_xor(eV, 1, 64);
        float qv   = odd ? fmaf(sn, part, cs * eV) : fmaf(cs, eV, -(sn * part));

        qv_lds[head][e] = qv;

        float num0 = 0.0f, num1 = 0.0f, num2 = 0.0f, num3 = 0.0f;
        float den0 = 0.0f, den1 = 0.0f, den2 = 0.0f, den3 = 0.0f;
        #pragma unroll
        for (int dq = 0; dq < 8; dq++) {
            float4 q4 = *(const float4*)&qv_lds[head][dq * 4];
            num0 = fmaf(q4.x, kvreg[dq * 4 + 0], num0);
            num1 = fmaf(q4.y, kvreg[dq * 4 + 1], num1);
            num2 = fmaf(q4.z, kvreg[dq * 4 + 2], num2);
            num3 = fmaf(q4.w, kvreg[dq * 4 + 3], num3);
            den0 = fmaf(q4.x, kmreg[dq * 4 + 0], den0);
            den1 = fmaf(q4.y, kmreg[dq * 4 + 1], den1);
            den2 = fmaf(q4.z, kmreg[dq * 4 + 2], den2);
            den3 = fmaf(q4.w, kmreg[dq * 4 + 3], den3);
        }
        float num = (num0 + num1) + (num2 + num3);
        float den = (den0 + den1) + (den2 + den3);
        float z = 1.0f / (den + 1e-6f);

        float lp = lb;
        lp = fmaf(x0m, w9[0], lp); lp = fmaf(x00, w9[1], lp); lp = fmaf(x0p, w9[2], lp);
        lp = fmaf(x1m, w9[3], lp); lp = fmaf(x10, w9[4], lp); lp = fmaf(x1p, w9[5], lp);
        lp = fmaf(x2m, w9[6], lp); lp = fmaf(x20, w9[7], lp);

        outb[(size_t)wg * 512] = fmaf(num, z, fmaf(x2p, w9[8], lp));

        qraw = qraw_n; ssp = ssp_n; cs = cs_n; sn = sn_n;
        x0m = x00; x00 = x0p;
        x1m = x10; x10 = x1p;
        x2m = x20; x20 = x2p;
    }
}

} // namespace

extern "C" void kernel_launch(void* const* d_in, const int* in_sizes, int n_in,
                              void* d_out, int out_size, void* d_ws, size_t ws_size,
                              hipStream_t stream)
{
    (void)in_sizes; (void)n_in; (void)out_size; (void)ws_size;
    const float* x        = (const float*)d_in[0];
    const float* qk_w     = (const float*)d_in[1];
    const float* qk_b     = (const float*)d_in[2];
    const float* qsp_dw_w = (const float*)d_in[3];
    const float* qsp_dw_b = (const float*)d_in[4];
    const float* qsp_bn_g = (const float*)d_in[5];
    const float* qsp_bn_b = (const float*)d_in[6];
    const float* qsp_pw_w = (const float*)d_in[7];
    const float* qch_w    = (const float*)d_in[8];
    const float* ksp_dw_w = (const float*)d_in[9];
    const float* ksp_dw_b = (const float*)d_in[10];
    const float* ksp_bn_g = (const float*)d_in[11];
    const float* ksp_bn_b = (const float*)d_in[12];
    const float* ksp_pw_w = (const float*)d_in[13];
    const float* kch_w    = (const float*)d_in[14];
    const float* lepe_w   = (const float*)d_in[15];
    const float* lepe_b   = (const float*)d_in[16];
    const float* rope_cos = (const float*)d_in[17];
    const float* rope_sin = (const float*)d_in[18];

    float* ws     = (float*)d_ws;
    float* qk     = ws;                       // 33554432 floats (128 MB)
    float* s_sp_q = qk + 33554432;            // 32768
    float* s_sp_k = s_sp_q + 32768;           // 32768
    float* sch_q  = s_sp_k + 32768;           // 4096
    float* sch_k  = sch_q + 4096;             // 4096
    float* pool_q = sch_k + 4096;             // 4096  <- zeroed region starts here
    float* pool_k = pool_q + 4096;            // 4096
    float* kmean  = pool_k + 4096;            // 4096
    float* kv     = kmean + 4096;             // 131072 (zeroed region: 143360 floats)
    _Float16* x_hi = (_Float16*)(kv + 131072);     // 32 MB
    _Float16* x_lo = x_hi + 16777216;              // 32 MB
    _Float16* w_hi = x_lo + 16777216;              // 1 MB
    _Float16* w_lo = w_hi + 524288;                // 1 MB

    // fused: zero accumulators (140 blocks) + split qk_w (512) + split x (16384)
    k_prep<<<17036, 256, 0, stream>>>(
        (const float4*)x, (const float4*)qk_w,
        (half4*)x_hi, (half4*)x_lo, (half4*)w_hi, (half4*)w_lo,
        (float4*)pool_q);

    k_gemm_mfma<<<dim3(256, 8), 256, 0, stream>>>(x_hi, x_lo, w_hi, w_lo, qk_b, qk);

    k_spatial<<<dim3(2048, 2), 512, 0, stream>>>(qk,
        qsp_dw_w, qsp_dw_b, qsp_bn_g, qsp_bn_b, qsp_pw_w,
        ksp_dw_w, ksp_dw_b, ksp_bn_g, ksp_bn_b, ksp_pw_w,
        s_sp_q, s_sp_k, pool_q, pool_k);
    k_chsig<<<2048, 256, 0, stream>>>(pool_q, pool_k, qch_w, kch_w, sch_q, sch_k);
    k_kv<<<dim3(128, 8), 256, 0, stream>>>(qk, x, s_sp_k, sch_k, rope_cos, rope_sin,
                                           kv, kmean);
    k_final<<<1024, 512, 0, stream>>>(qk, x, kv, kmean, s_sp_q, sch_q,
                                      rope_cos, rope_sin, lepe_w, lepe_b, (float*)d_out);
}